// Round 1
// baseline (935.213 us; speedup 1.0000x reference)
//
#include <hip/hip_runtime.h>

// ---------------------------------------------------------------------------
// GraphConvEncoder: 2-layer GraphConv
//   h  = relu( seg_sum(x[src])@W1_rel^T + b1 + x@W1_root^T )
//   out=       seg_sum(h[src])@W2_rel^T + b2 + h@W2_root^T
// Strategy: transform-then-aggregate (matmul commutes with segment_sum),
// CSR built on device each call (edge_index is input; no cross-call state).
// U1 = [y1 | z1] with y1 = x@W1_rel^T, z1 = b1 + x@W1_root^T  (N x 256)
// U2 = [y2 | z2] with y2 = h@W2_rel^T, z2 = b2 + h@W2_root^T  (N x 128)
// ---------------------------------------------------------------------------

#define KDIM 128
#define KP 32

// ---------------- CSR build ----------------

__global__ __launch_bounds__(256) void hist_kernel(const int* __restrict__ dst,
                                                   int E, int* __restrict__ deg) {
    int i = blockIdx.x * 256 + threadIdx.x;
    if (i < E) atomicAdd(&deg[dst[i]], 1);
}

__global__ __launch_bounds__(256) void block_sums(const int* __restrict__ deg,
                                                  int n, int* __restrict__ bsum) {
    __shared__ int s[256];
    int i = blockIdx.x * 256 + threadIdx.x;
    s[threadIdx.x] = (i < n) ? deg[i] : 0;
    __syncthreads();
    for (int off = 128; off > 0; off >>= 1) {
        if (threadIdx.x < off) s[threadIdx.x] += s[threadIdx.x + off];
        __syncthreads();
    }
    if (threadIdx.x == 0) bsum[blockIdx.x] = s[0];
}

__global__ __launch_bounds__(512) void scan_bsums(const int* __restrict__ bsum,
                                                  int nb, int* __restrict__ boff) {
    __shared__ int s[512];
    int t = threadIdx.x;
    s[t] = (t < nb) ? bsum[t] : 0;
    __syncthreads();
    for (int off = 1; off < 512; off <<= 1) {
        int v = (t >= off) ? s[t - off] : 0;
        __syncthreads();
        s[t] += v;
        __syncthreads();
    }
    if (t < nb) boff[t] = (t == 0) ? 0 : s[t - 1];
}

__global__ __launch_bounds__(256) void scan_final(const int* __restrict__ deg, int n,
                                                  const int* __restrict__ boff,
                                                  int* __restrict__ rowptr, int E) {
    __shared__ int s[256];
    int t = threadIdx.x;
    int i = blockIdx.x * 256 + t;
    int v = (i < n) ? deg[i] : 0;
    s[t] = v;
    __syncthreads();
    for (int off = 1; off < 256; off <<= 1) {
        int u = (t >= off) ? s[t - off] : 0;
        __syncthreads();
        s[t] += u;
        __syncthreads();
    }
    if (i < n) rowptr[i] = boff[blockIdx.x] + s[t] - v;  // exclusive scan
    if (blockIdx.x == 0 && t == 0) rowptr[n] = E;
}

__global__ __launch_bounds__(256) void fill_csr(const int* __restrict__ src,
                                                const int* __restrict__ dst, int E,
                                                const int* __restrict__ rowptr,
                                                int* __restrict__ off,
                                                int* __restrict__ col) {
    int i = blockIdx.x * 256 + threadIdx.x;
    if (i < E) {
        int d = dst[i];
        int p = atomicAdd(&off[d], 1);
        col[rowptr[d] + p] = src[i];
    }
}

// ---------------- dual GEMM: U = [X@Wa^T | bias + X@Wb^T] ----------------
// X: [n_rows, 128], Wa/Wb: [C, 128] row-major, U: [n_rows, 2C]
// block = 256 threads, tile = 64 rows x 2C cols, per-thread 8 x (2C/32)

template <int C>
__global__ __launch_bounds__(256) void gemm_dual(const float* __restrict__ X,
                                                 const float* __restrict__ Wa,
                                                 const float* __restrict__ Wb,
                                                 const float* __restrict__ bias,
                                                 float* __restrict__ U, int n_rows) {
    constexpr int NC = 2 * C;
    constexpr int TN = NC / 32;  // 8 (C=128) or 4 (C=64)
    constexpr int TM = 8;
    constexpr int WPAD = NC + 4;  // keeps float4 alignment, breaks pow2 stride

    __shared__ alignas(16) float Xs[64][33];
    __shared__ alignas(16) float Ws[KP][WPAD];

    const int t = threadIdx.x;
    const int tx = t & 31;
    const int ty = t >> 5;  // 0..7
    const int row0 = blockIdx.x * 64;

    float acc[TM][TN];
#pragma unroll
    for (int i = 0; i < TM; i++)
#pragma unroll
        for (int j = 0; j < TN; j++) acc[i][j] = 0.f;

    const int kk = t & 31;
    const int g0 = t >> 5;  // 0..7

    for (int kp = 0; kp < KDIM; kp += KP) {
        // stage X tile (coalesced along k)
#pragma unroll
        for (int m = 0; m < 64; m += 8) {
            int n = row0 + m + g0;
            Xs[m + g0][kk] = (n < n_rows) ? X[(long)n * KDIM + kp + kk] : 0.f;
        }
        // stage W' tile transposed (k-major) for float4 compute reads
#pragma unroll
        for (int j = 0; j < NC; j += 8) {
            int jj = j + g0;
            const float* Wr = (jj < C) ? (Wa + (long)jj * KDIM) : (Wb + (long)(jj - C) * KDIM);
            Ws[kk][jj] = Wr[kp + kk];
        }
        __syncthreads();

#pragma unroll
        for (int k2 = 0; k2 < KP; ++k2) {
            float a[TM];
#pragma unroll
            for (int mm = 0; mm < TM; mm++) a[mm] = Xs[ty * TM + mm][k2];
            float w[TN];
#pragma unroll
            for (int q = 0; q < TN; q += 4) {
                float4 wv = *(const float4*)&Ws[k2][tx * TN + q];
                w[q] = wv.x; w[q + 1] = wv.y; w[q + 2] = wv.z; w[q + 3] = wv.w;
            }
#pragma unroll
            for (int mm = 0; mm < TM; mm++)
#pragma unroll
                for (int jj = 0; jj < TN; jj++) acc[mm][jj] += a[mm] * w[jj];
        }
        __syncthreads();
    }

    // epilogue: add bias on the z-half (cols >= C), vectorized store
    const int j0 = tx * TN;
    float bv[TN];
#pragma unroll
    for (int jj = 0; jj < TN; jj++) bv[jj] = (j0 + jj >= C) ? bias[j0 + jj - C] : 0.f;
#pragma unroll
    for (int mm = 0; mm < TM; mm++) {
        int n = row0 + ty * TM + mm;
        if (n < n_rows) {
#pragma unroll
            for (int q = 0; q < TN; q += 4) {
                float4 v = {acc[mm][q] + bv[q], acc[mm][q + 1] + bv[q + 1],
                            acc[mm][q + 2] + bv[q + 2], acc[mm][q + 3] + bv[q + 3]};
                *(float4*)&U[(long)n * NC + j0 + q] = v;
            }
        }
    }
}

// ---------------- aggregation ----------------
// layer 1: one wave per node, 64 lanes x float2 over 128 channels.
// h[n] = relu( sum_{s in nbrs(n)} y1[s] + z1[n] )

__global__ __launch_bounds__(256) void agg_relu_l1(const float* __restrict__ U1,
                                                   const int* __restrict__ rowptr,
                                                   const int* __restrict__ col,
                                                   float* __restrict__ h, int n_nodes) {
    int node = (blockIdx.x * 256 + threadIdx.x) >> 6;
    if (node >= n_nodes) return;
    int lane = threadIdx.x & 63;
    const float2* Uv = (const float2*)U1;  // row = 128 float2; y=0..63, z=64..127
    int beg = rowptr[node], end = rowptr[node + 1];
    float ax = 0.f, ay = 0.f;
    int e = beg;
    for (; e + 4 <= end; e += 4) {
        int s0 = col[e], s1 = col[e + 1], s2 = col[e + 2], s3 = col[e + 3];
        float2 ga = Uv[(long)s0 * 128 + lane];
        float2 gb = Uv[(long)s1 * 128 + lane];
        float2 gc = Uv[(long)s2 * 128 + lane];
        float2 gd = Uv[(long)s3 * 128 + lane];
        ax += ga.x + gb.x + gc.x + gd.x;
        ay += ga.y + gb.y + gc.y + gd.y;
    }
    for (; e < end; ++e) {
        int s = col[e];
        float2 g = Uv[(long)s * 128 + lane];
        ax += g.x;
        ay += g.y;
    }
    float2 z = Uv[(long)node * 128 + 64 + lane];
    ax += z.x;
    ay += z.y;
    ax = ax > 0.f ? ax : 0.f;
    ay = ay > 0.f ? ay : 0.f;
    ((float2*)h)[(long)node * 64 + lane] = make_float2(ax, ay);
}

// layer 2: one wave per node, 64 lanes x float over 64 channels, no relu.
__global__ __launch_bounds__(256) void agg_l2(const float* __restrict__ U2,
                                              const int* __restrict__ rowptr,
                                              const int* __restrict__ col,
                                              float* __restrict__ out, int n_nodes) {
    int node = (blockIdx.x * 256 + threadIdx.x) >> 6;
    if (node >= n_nodes) return;
    int lane = threadIdx.x & 63;
    int beg = rowptr[node], end = rowptr[node + 1];
    float a = 0.f;
    int e = beg;
    for (; e + 4 <= end; e += 4) {
        int s0 = col[e], s1 = col[e + 1], s2 = col[e + 2], s3 = col[e + 3];
        a += U2[(long)s0 * 128 + lane] + U2[(long)s1 * 128 + lane] +
             U2[(long)s2 * 128 + lane] + U2[(long)s3 * 128 + lane];
    }
    for (; e < end; ++e) a += U2[(long)col[e] * 128 + lane];
    a += U2[(long)node * 128 + 64 + lane];
    out[(long)node * 64 + lane] = a;
}

// ---------------- launch ----------------

extern "C" void kernel_launch(void* const* d_in, const int* in_sizes, int n_in,
                              void* d_out, int out_size, void* d_ws, size_t ws_size,
                              hipStream_t stream) {
    const float* x       = (const float*)d_in[0];
    const int*   ei      = (const int*)d_in[1];
    const float* W1_rel  = (const float*)d_in[2];
    const float* b1      = (const float*)d_in[3];
    const float* W1_root = (const float*)d_in[4];
    const float* W2_rel  = (const float*)d_in[5];
    const float* b2      = (const float*)d_in[6];
    const float* W2_root = (const float*)d_in[7];
    float* out = (float*)d_out;

    const int N = in_sizes[0] / 128;
    const int E = in_sizes[1] / 2;
    const int* srcA = ei;
    const int* dstA = ei + E;

    char* ws = (char*)d_ws;
    size_t cur = 0;
    auto alloc = [&](size_t bytes) -> void* {
        size_t o = cur;
        cur = (cur + bytes + 511) & ~(size_t)511;
        return (void*)(ws + o);
    };
    float* U1   = (float*)alloc((size_t)N * 256 * 4);  // [y1|z1]
    float* h    = (float*)alloc((size_t)N * 128 * 4);
    int* deg    = (int*)alloc((size_t)N * 4);
    int* rowptr = (int*)alloc((size_t)(N + 1) * 4);
    int* off    = (int*)alloc((size_t)N * 4);
    int* colA   = (int*)alloc((size_t)E * 4);
    int* bsum   = (int*)alloc(512 * 4);
    int* boff   = (int*)alloc(512 * 4);
    float* U2 = U1;  // alias: U1 dead after agg_relu_l1

    hipMemsetAsync(deg, 0, (size_t)N * 4, stream);
    hipMemsetAsync(off, 0, (size_t)N * 4, stream);

    const int nb = (N + 255) / 256;
    hist_kernel<<<(E + 255) / 256, 256, 0, stream>>>(dstA, E, deg);
    block_sums<<<nb, 256, 0, stream>>>(deg, N, bsum);
    scan_bsums<<<1, 512, 0, stream>>>(bsum, nb, boff);
    scan_final<<<nb, 256, 0, stream>>>(deg, N, boff, rowptr, E);
    fill_csr<<<(E + 255) / 256, 256, 0, stream>>>(srcA, dstA, E, rowptr, off, colA);

    gemm_dual<128><<<(N + 63) / 64, 256, 0, stream>>>(x, W1_rel, W1_root, b1, U1, N);
    agg_relu_l1<<<(N + 3) / 4, 256, 0, stream>>>(U1, rowptr, colA, h, N);
    gemm_dual<64><<<(N + 63) / 64, 256, 0, stream>>>(h, W2_rel, W2_root, b2, U2, N);
    agg_l2<<<(N + 3) / 4, 256, 0, stream>>>(U2, rowptr, colA, out, N);
}

// Round 2
// 840.136 us; speedup vs baseline: 1.1132x; 1.1132x over previous
//
#include <hip/hip_runtime.h>
#include <hip/hip_bf16.h>

// ---------------------------------------------------------------------------
// GraphConvEncoder: 2-layer GraphConv, transform-then-aggregate.
// y = x@W_rel^T stored bf16 (gathered E times); z = b + x@W_root^T fp32.
// h = relu(gather_sum(y1) + z1) fp32; out = gather_sum(y2) + z2 fp32.
// ---------------------------------------------------------------------------

#define KDIM 128
#define KP 32

// ---------------- CSR build ----------------

__global__ __launch_bounds__(256) void hist_kernel(const int* __restrict__ dst,
                                                   int E, int* __restrict__ deg) {
    int i = blockIdx.x * 256 + threadIdx.x;
    if (i < E) atomicAdd(&deg[dst[i]], 1);
}

__global__ __launch_bounds__(256) void block_sums(const int* __restrict__ deg,
                                                  int n, int* __restrict__ bsum) {
    __shared__ int s[256];
    int i = blockIdx.x * 256 + threadIdx.x;
    s[threadIdx.x] = (i < n) ? deg[i] : 0;
    __syncthreads();
    for (int off = 128; off > 0; off >>= 1) {
        if (threadIdx.x < off) s[threadIdx.x] += s[threadIdx.x + off];
        __syncthreads();
    }
    if (threadIdx.x == 0) bsum[blockIdx.x] = s[0];
}

__global__ __launch_bounds__(512) void scan_bsums(const int* __restrict__ bsum,
                                                  int nb, int* __restrict__ boff) {
    __shared__ int s[512];
    int t = threadIdx.x;
    s[t] = (t < nb) ? bsum[t] : 0;
    __syncthreads();
    for (int off = 1; off < 512; off <<= 1) {
        int v = (t >= off) ? s[t - off] : 0;
        __syncthreads();
        s[t] += v;
        __syncthreads();
    }
    if (t < nb) boff[t] = (t == 0) ? 0 : s[t - 1];
}

__global__ __launch_bounds__(256) void scan_final(const int* __restrict__ deg, int n,
                                                  const int* __restrict__ boff,
                                                  int* __restrict__ rowptr, int E) {
    __shared__ int s[256];
    int t = threadIdx.x;
    int i = blockIdx.x * 256 + t;
    int v = (i < n) ? deg[i] : 0;
    s[t] = v;
    __syncthreads();
    for (int off = 1; off < 256; off <<= 1) {
        int u = (t >= off) ? s[t - off] : 0;
        __syncthreads();
        s[t] += u;
        __syncthreads();
    }
    if (i < n) rowptr[i] = boff[blockIdx.x] + s[t] - v;  // exclusive scan
    if (blockIdx.x == 0 && t == 0) rowptr[n] = E;
}

__global__ __launch_bounds__(256) void fill_csr(const int* __restrict__ src,
                                                const int* __restrict__ dst, int E,
                                                const int* __restrict__ rowptr,
                                                int* __restrict__ off,
                                                int* __restrict__ col) {
    int i = blockIdx.x * 256 + threadIdx.x;
    if (i < E) {
        int d = dst[i];
        int p = atomicAdd(&off[d], 1);
        col[rowptr[d] + p] = src[i];
    }
}

// ---------------- dual GEMM: Y = bf16(X@Wa^T), Z = bias + X@Wb^T ----------------
// X: [n_rows, 128] fp32, Wa/Wb: [C, 128] row-major.
// Y: [n_rows, C] bf16, Z: [n_rows, C] fp32.
// block = 256 threads, tile = 64 rows x 2C cols, per-thread 8 x (2C/32).

template <int C>
__global__ __launch_bounds__(256) void gemm_dual(const float* __restrict__ X,
                                                 const float* __restrict__ Wa,
                                                 const float* __restrict__ Wb,
                                                 const float* __restrict__ bias,
                                                 ushort* __restrict__ Y,
                                                 float* __restrict__ Z, int n_rows) {
    constexpr int NC = 2 * C;
    constexpr int TN = NC / 32;  // 8 (C=128) or 4 (C=64)
    constexpr int TM = 8;
    constexpr int WPAD = NC + 4;

    __shared__ alignas(16) float Xs[64][33];
    __shared__ alignas(16) float Ws[KP][WPAD];

    const int t = threadIdx.x;
    const int tx = t & 31;
    const int ty = t >> 5;  // 0..7
    const int row0 = blockIdx.x * 64;

    float acc[TM][TN];
#pragma unroll
    for (int i = 0; i < TM; i++)
#pragma unroll
        for (int j = 0; j < TN; j++) acc[i][j] = 0.f;

    const int kk = t & 31;
    const int g0 = t >> 5;  // 0..7

    for (int kp = 0; kp < KDIM; kp += KP) {
#pragma unroll
        for (int m = 0; m < 64; m += 8) {
            int n = row0 + m + g0;
            Xs[m + g0][kk] = (n < n_rows) ? X[(long)n * KDIM + kp + kk] : 0.f;
        }
#pragma unroll
        for (int j = 0; j < NC; j += 8) {
            int jj = j + g0;
            const float* Wr = (jj < C) ? (Wa + (long)jj * KDIM) : (Wb + (long)(jj - C) * KDIM);
            Ws[kk][jj] = Wr[kp + kk];
        }
        __syncthreads();

#pragma unroll
        for (int k2 = 0; k2 < KP; ++k2) {
            float a[TM];
#pragma unroll
            for (int mm = 0; mm < TM; mm++) a[mm] = Xs[ty * TM + mm][k2];
            float w[TN];
#pragma unroll
            for (int q = 0; q < TN; q += 4) {
                float4 wv = *(const float4*)&Ws[k2][tx * TN + q];
                w[q] = wv.x; w[q + 1] = wv.y; w[q + 2] = wv.z; w[q + 3] = wv.w;
            }
#pragma unroll
            for (int mm = 0; mm < TM; mm++)
#pragma unroll
                for (int jj = 0; jj < TN; jj++) acc[mm][jj] += a[mm] * w[jj];
        }
        __syncthreads();
    }

    // epilogue: tx<16 -> y-half (bf16, cols j0..j0+TN-1 < C); tx>=16 -> z-half (+bias)
    const int j0 = tx * TN;
    if (j0 < C) {
#pragma unroll
        for (int mm = 0; mm < TM; mm++) {
            int n = row0 + ty * TM + mm;
            if (n < n_rows) {
                uint p[TN / 2];
#pragma unroll
                for (int q = 0; q < TN; q += 2) {
                    __hip_bfloat162 b2 = __float22bfloat162_rn(
                        make_float2(acc[mm][q], acc[mm][q + 1]));
                    p[q / 2] = *(uint*)&b2;  // low = col q (even), high = col q+1
                }
                uint* dstp = (uint*)&Y[(long)n * C + j0];
#pragma unroll
                for (int q = 0; q < TN / 2; q++) dstp[q] = p[q];
            }
        }
    } else {
        const int jz = j0 - C;
        float bv[TN];
#pragma unroll
        for (int jj = 0; jj < TN; jj++) bv[jj] = bias[jz + jj];
#pragma unroll
        for (int mm = 0; mm < TM; mm++) {
            int n = row0 + ty * TM + mm;
            if (n < n_rows) {
#pragma unroll
                for (int q = 0; q < TN; q += 4) {
                    float4 v = {acc[mm][q] + bv[q], acc[mm][q + 1] + bv[q + 1],
                                acc[mm][q + 2] + bv[q + 2], acc[mm][q + 3] + bv[q + 3]};
                    *(float4*)&Z[(long)n * C + jz + q] = v;
                }
            }
        }
    }
}

__device__ __forceinline__ float bflo(uint g) { return __uint_as_float(g << 16); }
__device__ __forceinline__ float bfhi(uint g) { return __uint_as_float(g & 0xffff0000u); }

// ---------------- aggregation ----------------
// layer 1: one wave per node, lane handles channels 2*lane, 2*lane+1 (one uint).

__global__ __launch_bounds__(256) void agg_relu_l1(const ushort* __restrict__ Y1,
                                                   const float* __restrict__ Z1,
                                                   const int* __restrict__ rowptr,
                                                   const int* __restrict__ col,
                                                   float* __restrict__ h, int n_nodes) {
    int node = (blockIdx.x * 256 + threadIdx.x) >> 6;
    if (node >= n_nodes) return;
    int lane = threadIdx.x & 63;
    const uint* Yv = (const uint*)Y1;  // row = 64 uints (128 bf16)
    int beg = rowptr[node], end = rowptr[node + 1];
    float ax = 0.f, ay = 0.f;
    int e = beg;
    for (; e + 4 <= end; e += 4) {
        int s0 = col[e], s1 = col[e + 1], s2 = col[e + 2], s3 = col[e + 3];
        uint ga = Yv[(long)s0 * 64 + lane];
        uint gb = Yv[(long)s1 * 64 + lane];
        uint gc = Yv[(long)s2 * 64 + lane];
        uint gd = Yv[(long)s3 * 64 + lane];
        ax += bflo(ga) + bflo(gb) + bflo(gc) + bflo(gd);
        ay += bfhi(ga) + bfhi(gb) + bfhi(gc) + bfhi(gd);
    }
    for (; e < end; ++e) {
        uint g = Yv[(long)col[e] * 64 + lane];
        ax += bflo(g);
        ay += bfhi(g);
    }
    float2 z = ((const float2*)Z1)[(long)node * 64 + lane];
    ax += z.x;
    ay += z.y;
    ax = ax > 0.f ? ax : 0.f;
    ay = ay > 0.f ? ay : 0.f;
    ((float2*)h)[(long)node * 64 + lane] = make_float2(ax, ay);
}

// layer 2: one wave per node, lane handles channel `lane` (one ushort).
__global__ __launch_bounds__(256) void agg_l2(const ushort* __restrict__ Y2,
                                              const float* __restrict__ Z2,
                                              const int* __restrict__ rowptr,
                                              const int* __restrict__ col,
                                              float* __restrict__ out, int n_nodes) {
    int node = (blockIdx.x * 256 + threadIdx.x) >> 6;
    if (node >= n_nodes) return;
    int lane = threadIdx.x & 63;
    int beg = rowptr[node], end = rowptr[node + 1];
    float a = 0.f;
    int e = beg;
    for (; e + 4 <= end; e += 4) {
        int s0 = col[e], s1 = col[e + 1], s2 = col[e + 2], s3 = col[e + 3];
        float f0 = __uint_as_float((uint)Y2[(long)s0 * 64 + lane] << 16);
        float f1 = __uint_as_float((uint)Y2[(long)s1 * 64 + lane] << 16);
        float f2 = __uint_as_float((uint)Y2[(long)s2 * 64 + lane] << 16);
        float f3 = __uint_as_float((uint)Y2[(long)s3 * 64 + lane] << 16);
        a += f0 + f1 + f2 + f3;
    }
    for (; e < end; ++e)
        a += __uint_as_float((uint)Y2[(long)col[e] * 64 + lane] << 16);
    a += Z2[(long)node * 64 + lane];
    out[(long)node * 64 + lane] = a;
}

// ---------------- launch ----------------

extern "C" void kernel_launch(void* const* d_in, const int* in_sizes, int n_in,
                              void* d_out, int out_size, void* d_ws, size_t ws_size,
                              hipStream_t stream) {
    const float* x       = (const float*)d_in[0];
    const int*   ei      = (const int*)d_in[1];
    const float* W1_rel  = (const float*)d_in[2];
    const float* b1      = (const float*)d_in[3];
    const float* W1_root = (const float*)d_in[4];
    const float* W2_rel  = (const float*)d_in[5];
    const float* b2      = (const float*)d_in[6];
    const float* W2_root = (const float*)d_in[7];
    float* out = (float*)d_out;

    const int N = in_sizes[0] / 128;
    const int E = in_sizes[1] / 2;
    const int* srcA = ei;
    const int* dstA = ei + E;

    char* ws = (char*)d_ws;
    size_t cur = 0;
    auto alloc = [&](size_t bytes) -> void* {
        size_t o = cur;
        cur = (cur + bytes + 511) & ~(size_t)511;
        return (void*)(ws + o);
    };
    ushort* Y1  = (ushort*)alloc((size_t)N * 128 * 2);
    float*  Z1  = (float*)alloc((size_t)N * 128 * 4);
    float*  h   = (float*)alloc((size_t)N * 128 * 4);
    int* deg    = (int*)alloc((size_t)N * 4);
    int* rowptr = (int*)alloc((size_t)(N + 1) * 4);
    int* off    = (int*)alloc((size_t)N * 4);
    int* colA   = (int*)alloc((size_t)E * 4);
    int* bsum   = (int*)alloc(512 * 4);
    int* boff   = (int*)alloc(512 * 4);
    ushort* Y2 = Y1;           // alias: Y1/Z1 dead after agg_relu_l1
    float*  Z2 = Z1;

    hipMemsetAsync(deg, 0, (size_t)N * 4, stream);
    hipMemsetAsync(off, 0, (size_t)N * 4, stream);

    const int nb = (N + 255) / 256;
    hist_kernel<<<(E + 255) / 256, 256, 0, stream>>>(dstA, E, deg);
    block_sums<<<nb, 256, 0, stream>>>(deg, N, bsum);
    scan_bsums<<<1, 512, 0, stream>>>(bsum, nb, boff);
    scan_final<<<nb, 256, 0, stream>>>(deg, N, boff, rowptr, E);
    fill_csr<<<(E + 255) / 256, 256, 0, stream>>>(srcA, dstA, E, rowptr, off, colA);

    gemm_dual<128><<<(N + 63) / 64, 256, 0, stream>>>(x, W1_rel, W1_root, b1, Y1, Z1, N);
    agg_relu_l1<<<(N + 3) / 4, 256, 0, stream>>>(Y1, Z1, rowptr, colA, h, N);
    gemm_dual<64><<<(N + 63) / 64, 256, 0, stream>>>(h, W2_rel, W2_root, b2, Y2, Z2, N);
    agg_l2<<<(N + 3) / 4, 256, 0, stream>>>(Y2, Z2, rowptr, colA, out, N);
}

// Round 3
// 644.827 us; speedup vs baseline: 1.4503x; 1.3029x over previous
//
#include <hip/hip_runtime.h>
#include <hip/hip_bf16.h>

// ---------------------------------------------------------------------------
// GraphConvEncoder: 2-layer GraphConv, transform-then-aggregate.
// y = x@W_rel^T stored bf16 (gathered E times); z = b + x@W_root^T fp32.
// h = relu(gather_sum(y1) + z1) fp32; out = gather_sum(y2) + z2 fp32.
// CSR built via bucketed multisplit (bucket = dst>>8) — no global atomics,
// coalesced/bucket-local writes (R2's fill_csr had 192 MB write-amp).
// ---------------------------------------------------------------------------

#define KDIM 128
#define KP 32
#define EB 8192       // edges per block in bucket passes
#define NB_MAX 512    // max buckets (N <= 131072)

// ---------------- CSR build: bucketed multisplit ----------------

// hist[blk*NB + bucket] = #edges of block blk with dst>>8 == bucket
__global__ __launch_bounds__(256) void bucket_hist(const int* __restrict__ dst, int E,
                                                   int NB, int* __restrict__ hist) {
    __shared__ int h[NB_MAX];
    int t = threadIdx.x;
    for (int i = t; i < NB; i += 256) h[i] = 0;
    __syncthreads();
    int e0 = blockIdx.x * EB, e1 = min(E, e0 + EB);
    for (int e = e0 + t; e < e1; e += 256) atomicAdd(&h[dst[e] >> 8], 1);
    __syncthreads();
    int* row = hist + (size_t)blockIdx.x * NB;
    for (int i = t; i < NB; i += 256) row[i] = h[i];
}

// per bucket: exclusive prefix over blocks (in place), total[bucket] = sum
__global__ __launch_bounds__(256) void scan_blocks(int* __restrict__ hist, int NBLK,
                                                   int NB, int* __restrict__ total) {
    __shared__ int s[256];
    __shared__ int carry;
    int b = blockIdx.x, t = threadIdx.x;
    if (t == 0) carry = 0;
    __syncthreads();
    for (int start = 0; start < NBLK; start += 256) {
        int i = start + t;
        int v = (i < NBLK) ? hist[(size_t)i * NB + b] : 0;
        s[t] = v;
        __syncthreads();
        for (int off = 1; off < 256; off <<= 1) {
            int u = (t >= off) ? s[t - off] : 0;
            __syncthreads();
            s[t] += u;
            __syncthreads();
        }
        if (i < NBLK) hist[(size_t)i * NB + b] = carry + s[t] - v;
        __syncthreads();
        if (t == 255) carry += s[255];
        __syncthreads();
    }
    if (t == 0) total[b] = carry;
}

// exclusive scan of total[NB] -> base[NB]
__global__ __launch_bounds__(512) void scan_total(const int* __restrict__ total, int NB,
                                                  int* __restrict__ base) {
    __shared__ int s[512];
    int t = threadIdx.x;
    int v = (t < NB) ? total[t] : 0;
    s[t] = v;
    __syncthreads();
    for (int off = 1; off < 512; off <<= 1) {
        int u = (t >= off) ? s[t - off] : 0;
        __syncthreads();
        s[t] += u;
        __syncthreads();
    }
    if (t < NB) base[t] = s[t] - v;
}

// scatter edges into bucket-grouped ebuf: (local_dst<<24) | src
__global__ __launch_bounds__(256) void bucket_scatter(const int* __restrict__ src,
                                                      const int* __restrict__ dst, int E,
                                                      int NB, const int* __restrict__ hist,
                                                      const int* __restrict__ base,
                                                      uint* __restrict__ ebuf) {
    __shared__ int cur[NB_MAX];
    int t = threadIdx.x, blk = blockIdx.x;
    const int* row = hist + (size_t)blk * NB;
    for (int i = t; i < NB; i += 256) cur[i] = base[i] + row[i];
    __syncthreads();
    int e0 = blk * EB, e1 = min(E, e0 + EB);
    for (int e = e0 + t; e < e1; e += 256) {
        int d = dst[e];
        int p = atomicAdd(&cur[d >> 8], 1);
        ebuf[p] = ((uint)(d & 255) << 24) | (uint)src[e];
    }
}

// one block per bucket: rowptr for its 256 nodes + scatter src into its col window
__global__ __launch_bounds__(256) void build_csr_bucket(const uint* __restrict__ ebuf,
                                                        const int* __restrict__ base,
                                                        const int* __restrict__ total,
                                                        int NB, int N, int E,
                                                        int* __restrict__ rowptr,
                                                        int* __restrict__ col) {
    __shared__ int cnt[256];
    __shared__ int s[256];
    __shared__ int cur[256];
    int b = blockIdx.x, t = threadIdx.x;
    int e0 = base[b], e1 = e0 + total[b];
    cnt[t] = 0;
    __syncthreads();
    for (int e = e0 + t; e < e1; e += 256) atomicAdd(&cnt[ebuf[e] >> 24], 1);
    __syncthreads();
    int v = cnt[t];
    s[t] = v;
    __syncthreads();
    for (int off = 1; off < 256; off <<= 1) {
        int u = (t >= off) ? s[t - off] : 0;
        __syncthreads();
        s[t] += u;
        __syncthreads();
    }
    int start = e0 + s[t] - v;  // exclusive
    int node = (b << 8) + t;
    if (node < N) rowptr[node] = start;
    if (b == NB - 1 && t == 0) rowptr[N] = E;
    cur[t] = start;
    __syncthreads();
    for (int e = e0 + t; e < e1; e += 256) {
        uint ev = ebuf[e];
        int p = atomicAdd(&cur[ev >> 24], 1);
        col[p] = (int)(ev & 0xFFFFFFu);
    }
}

// ---------------- dual GEMM: Y = bf16(X@Wa^T), Z = bias + X@Wb^T ----------------

template <int C>
__global__ __launch_bounds__(256) void gemm_dual(const float* __restrict__ X,
                                                 const float* __restrict__ Wa,
                                                 const float* __restrict__ Wb,
                                                 const float* __restrict__ bias,
                                                 ushort* __restrict__ Y,
                                                 float* __restrict__ Z, int n_rows) {
    constexpr int NC = 2 * C;
    constexpr int TN = NC / 32;  // 8 (C=128) or 4 (C=64)
    constexpr int TM = 8;
    constexpr int WPAD = NC + 4;

    __shared__ alignas(16) float Xs[64][33];
    __shared__ alignas(16) float Ws[KP][WPAD];

    const int t = threadIdx.x;
    const int tx = t & 31;
    const int ty = t >> 5;  // 0..7
    const int row0 = blockIdx.x * 64;

    float acc[TM][TN];
#pragma unroll
    for (int i = 0; i < TM; i++)
#pragma unroll
        for (int j = 0; j < TN; j++) acc[i][j] = 0.f;

    const int kk = t & 31;
    const int g0 = t >> 5;  // 0..7

    for (int kp = 0; kp < KDIM; kp += KP) {
#pragma unroll
        for (int m = 0; m < 64; m += 8) {
            int n = row0 + m + g0;
            Xs[m + g0][kk] = (n < n_rows) ? X[(long)n * KDIM + kp + kk] : 0.f;
        }
#pragma unroll
        for (int j = 0; j < NC; j += 8) {
            int jj = j + g0;
            const float* Wr = (jj < C) ? (Wa + (long)jj * KDIM) : (Wb + (long)(jj - C) * KDIM);
            Ws[kk][jj] = Wr[kp + kk];
        }
        __syncthreads();

#pragma unroll
        for (int k2 = 0; k2 < KP; ++k2) {
            float a[TM];
#pragma unroll
            for (int mm = 0; mm < TM; mm++) a[mm] = Xs[ty * TM + mm][k2];
            float w[TN];
#pragma unroll
            for (int q = 0; q < TN; q += 4) {
                float4 wv = *(const float4*)&Ws[k2][tx * TN + q];
                w[q] = wv.x; w[q + 1] = wv.y; w[q + 2] = wv.z; w[q + 3] = wv.w;
            }
#pragma unroll
            for (int mm = 0; mm < TM; mm++)
#pragma unroll
                for (int jj = 0; jj < TN; jj++) acc[mm][jj] += a[mm] * w[jj];
        }
        __syncthreads();
    }

    const int j0 = tx * TN;
    if (j0 < C) {
#pragma unroll
        for (int mm = 0; mm < TM; mm++) {
            int n = row0 + ty * TM + mm;
            if (n < n_rows) {
                uint p[TN / 2];
#pragma unroll
                for (int q = 0; q < TN; q += 2) {
                    __hip_bfloat162 b2 = __float22bfloat162_rn(
                        make_float2(acc[mm][q], acc[mm][q + 1]));
                    p[q / 2] = *(uint*)&b2;
                }
                uint* dstp = (uint*)&Y[(long)n * C + j0];
#pragma unroll
                for (int q = 0; q < TN / 2; q++) dstp[q] = p[q];
            }
        }
    } else {
        const int jz = j0 - C;
        float bv[TN];
#pragma unroll
        for (int jj = 0; jj < TN; jj++) bv[jj] = bias[jz + jj];
#pragma unroll
        for (int mm = 0; mm < TM; mm++) {
            int n = row0 + ty * TM + mm;
            if (n < n_rows) {
#pragma unroll
                for (int q = 0; q < TN; q += 4) {
                    float4 v = {acc[mm][q] + bv[q], acc[mm][q + 1] + bv[q + 1],
                                acc[mm][q + 2] + bv[q + 2], acc[mm][q + 3] + bv[q + 3]};
                    *(float4*)&Z[(long)n * C + jz + q] = v;
                }
            }
        }
    }
}

__device__ __forceinline__ float bflo(uint g) { return __uint_as_float(g << 16); }
__device__ __forceinline__ float bfhi(uint g) { return __uint_as_float(g & 0xffff0000u); }

// ---------------- aggregation ----------------

__global__ __launch_bounds__(256) void agg_relu_l1(const ushort* __restrict__ Y1,
                                                   const float* __restrict__ Z1,
                                                   const int* __restrict__ rowptr,
                                                   const int* __restrict__ col,
                                                   float* __restrict__ h, int n_nodes) {
    int node = (blockIdx.x * 256 + threadIdx.x) >> 6;
    if (node >= n_nodes) return;
    int lane = threadIdx.x & 63;
    const uint* Yv = (const uint*)Y1;  // row = 64 uints (128 bf16)
    int beg = rowptr[node], end = rowptr[node + 1];
    float ax = 0.f, ay = 0.f;
    int e = beg;
    for (; e + 4 <= end; e += 4) {
        int s0 = col[e], s1 = col[e + 1], s2 = col[e + 2], s3 = col[e + 3];
        uint ga = Yv[(long)s0 * 64 + lane];
        uint gb = Yv[(long)s1 * 64 + lane];
        uint gc = Yv[(long)s2 * 64 + lane];
        uint gd = Yv[(long)s3 * 64 + lane];
        ax += bflo(ga) + bflo(gb) + bflo(gc) + bflo(gd);
        ay += bfhi(ga) + bfhi(gb) + bfhi(gc) + bfhi(gd);
    }
    for (; e < end; ++e) {
        uint g = Yv[(long)col[e] * 64 + lane];
        ax += bflo(g);
        ay += bfhi(g);
    }
    float2 z = ((const float2*)Z1)[(long)node * 64 + lane];
    ax += z.x;
    ay += z.y;
    ax = ax > 0.f ? ax : 0.f;
    ay = ay > 0.f ? ay : 0.f;
    ((float2*)h)[(long)node * 64 + lane] = make_float2(ax, ay);
}

__global__ __launch_bounds__(256) void agg_l2(const ushort* __restrict__ Y2,
                                              const float* __restrict__ Z2,
                                              const int* __restrict__ rowptr,
                                              const int* __restrict__ col,
                                              float* __restrict__ out, int n_nodes) {
    int node = (blockIdx.x * 256 + threadIdx.x) >> 6;
    if (node >= n_nodes) return;
    int lane = threadIdx.x & 63;
    int beg = rowptr[node], end = rowptr[node + 1];
    float a = 0.f;
    int e = beg;
    for (; e + 4 <= end; e += 4) {
        int s0 = col[e], s1 = col[e + 1], s2 = col[e + 2], s3 = col[e + 3];
        float f0 = __uint_as_float((uint)Y2[(long)s0 * 64 + lane] << 16);
        float f1 = __uint_as_float((uint)Y2[(long)s1 * 64 + lane] << 16);
        float f2 = __uint_as_float((uint)Y2[(long)s2 * 64 + lane] << 16);
        float f3 = __uint_as_float((uint)Y2[(long)s3 * 64 + lane] << 16);
        a += f0 + f1 + f2 + f3;
    }
    for (; e < end; ++e)
        a += __uint_as_float((uint)Y2[(long)col[e] * 64 + lane] << 16);
    a += Z2[(long)node * 64 + lane];
    out[(long)node * 64 + lane] = a;
}

// ---------------- launch ----------------

extern "C" void kernel_launch(void* const* d_in, const int* in_sizes, int n_in,
                              void* d_out, int out_size, void* d_ws, size_t ws_size,
                              hipStream_t stream) {
    const float* x       = (const float*)d_in[0];
    const int*   ei      = (const int*)d_in[1];
    const float* W1_rel  = (const float*)d_in[2];
    const float* b1      = (const float*)d_in[3];
    const float* W1_root = (const float*)d_in[4];
    const float* W2_rel  = (const float*)d_in[5];
    const float* b2      = (const float*)d_in[6];
    const float* W2_root = (const float*)d_in[7];
    float* out = (float*)d_out;

    const int N = in_sizes[0] / 128;
    const int E = in_sizes[1] / 2;
    const int* srcA = ei;
    const int* dstA = ei + E;
    const int NB   = (N + 255) >> 8;       // buckets of 256 nodes
    const int NBLK = (E + EB - 1) / EB;    // edge blocks

    char* ws = (char*)d_ws;
    size_t cur = 0;
    auto alloc = [&](size_t bytes) -> void* {
        size_t o = cur;
        cur = (cur + bytes + 511) & ~(size_t)511;
        return (void*)(ws + o);
    };
    ushort* Y1  = (ushort*)alloc((size_t)N * 128 * 2);
    float*  Z1  = (float*)alloc((size_t)N * 128 * 4);
    float*  h   = (float*)alloc((size_t)N * 128 * 4);
    int* rowptr = (int*)alloc((size_t)(N + 1) * 4);
    int* colA   = (int*)alloc((size_t)E * 4);
    int* hist   = (int*)alloc((size_t)NBLK * NB * 4);
    int* btotal = (int*)alloc((size_t)NB_MAX * 4);
    int* bbase  = (int*)alloc((size_t)NB_MAX * 4);
    uint* ebuf  = (uint*)h;  // alias: ebuf dead before h is written
    ushort* Y2 = Y1;         // alias: Y1/Z1 dead after agg_relu_l1
    float*  Z2 = Z1;

    bucket_hist<<<NBLK, 256, 0, stream>>>(dstA, E, NB, hist);
    scan_blocks<<<NB, 256, 0, stream>>>(hist, NBLK, NB, btotal);
    scan_total<<<1, 512, 0, stream>>>(btotal, NB, bbase);
    bucket_scatter<<<NBLK, 256, 0, stream>>>(srcA, dstA, E, NB, hist, bbase, ebuf);
    build_csr_bucket<<<NB, 256, 0, stream>>>(ebuf, bbase, btotal, NB, N, E, rowptr, colA);

    gemm_dual<128><<<(N + 63) / 64, 256, 0, stream>>>(x, W1_rel, W1_root, b1, Y1, Z1, N);
    agg_relu_l1<<<(N + 3) / 4, 256, 0, stream>>>(Y1, Z1, rowptr, colA, h, N);
    gemm_dual<64><<<(N + 63) / 64, 256, 0, stream>>>(h, W2_rel, W2_root, b2, Y2, Z2, N);
    agg_l2<<<(N + 3) / 4, 256, 0, stream>>>(Y2, Z2, rowptr, colA, out, N);
}

// Round 4
// 523.714 us; speedup vs baseline: 1.7857x; 1.2313x over previous
//
#include <hip/hip_runtime.h>
#include <hip/hip_bf16.h>

// ---------------------------------------------------------------------------
// GraphConvEncoder: 2-layer GraphConv, transform-then-aggregate.
// GEMMs via bf16 MFMA (16x16x32), fp32 accumulate.
// y = x@W_rel^T stored bf16 (gathered E times); z = b + x@W_root^T fp32.
// h = relu(gather_sum(y1) + z1) stored bf16; out = gather_sum(y2) + z2 fp32.
// CSR via bucketed multisplit (no global atomics, no write-amp).
// ---------------------------------------------------------------------------

#define EB 8192       // edges per block in bucket passes
#define NB_MAX 512    // max buckets (N <= 131072)

typedef __attribute__((ext_vector_type(8))) short bf16x8;
typedef __attribute__((ext_vector_type(4))) float f32x4;

__device__ __forceinline__ uint pack_bf16x2(float a, float b) {
    __hip_bfloat162 p = __float22bfloat162_rn(make_float2(a, b));
    return *(uint*)&p;  // low = a, high = b
}

// ---------------- CSR build: bucketed multisplit ----------------

__global__ __launch_bounds__(256) void bucket_hist(const int* __restrict__ dst, int E,
                                                   int NB, int* __restrict__ hist) {
    __shared__ int h[NB_MAX];
    int t = threadIdx.x;
    for (int i = t; i < NB; i += 256) h[i] = 0;
    __syncthreads();
    int e0 = blockIdx.x * EB, e1 = min(E, e0 + EB);
    for (int e = e0 + t; e < e1; e += 256) atomicAdd(&h[dst[e] >> 8], 1);
    __syncthreads();
    int* row = hist + (size_t)blockIdx.x * NB;
    for (int i = t; i < NB; i += 256) row[i] = h[i];
}

__global__ __launch_bounds__(256) void scan_blocks(int* __restrict__ hist, int NBLK,
                                                   int NB, int* __restrict__ total) {
    __shared__ int s[256];
    __shared__ int carry;
    int b = blockIdx.x, t = threadIdx.x;
    if (t == 0) carry = 0;
    __syncthreads();
    for (int start = 0; start < NBLK; start += 256) {
        int i = start + t;
        int v = (i < NBLK) ? hist[(size_t)i * NB + b] : 0;
        s[t] = v;
        __syncthreads();
        for (int off = 1; off < 256; off <<= 1) {
            int u = (t >= off) ? s[t - off] : 0;
            __syncthreads();
            s[t] += u;
            __syncthreads();
        }
        if (i < NBLK) hist[(size_t)i * NB + b] = carry + s[t] - v;
        __syncthreads();
        if (t == 255) carry += s[255];
        __syncthreads();
    }
    if (t == 0) total[b] = carry;
}

__global__ __launch_bounds__(512) void scan_total(const int* __restrict__ total, int NB,
                                                  int* __restrict__ base) {
    __shared__ int s[512];
    int t = threadIdx.x;
    int v = (t < NB) ? total[t] : 0;
    s[t] = v;
    __syncthreads();
    for (int off = 1; off < 512; off <<= 1) {
        int u = (t >= off) ? s[t - off] : 0;
        __syncthreads();
        s[t] += u;
        __syncthreads();
    }
    if (t < NB) base[t] = s[t] - v;
}

__global__ __launch_bounds__(256) void bucket_scatter(const int* __restrict__ src,
                                                      const int* __restrict__ dst, int E,
                                                      int NB, const int* __restrict__ hist,
                                                      const int* __restrict__ base,
                                                      uint* __restrict__ ebuf) {
    __shared__ int cur[NB_MAX];
    int t = threadIdx.x, blk = blockIdx.x;
    const int* row = hist + (size_t)blk * NB;
    for (int i = t; i < NB; i += 256) cur[i] = base[i] + row[i];
    __syncthreads();
    int e0 = blk * EB, e1 = min(E, e0 + EB);
    for (int e = e0 + t; e < e1; e += 256) {
        int d = dst[e];
        int p = atomicAdd(&cur[d >> 8], 1);
        ebuf[p] = ((uint)(d & 255) << 24) | (uint)src[e];
    }
}

__global__ __launch_bounds__(256) void build_csr_bucket(const uint* __restrict__ ebuf,
                                                        const int* __restrict__ base,
                                                        const int* __restrict__ total,
                                                        int NB, int N, int E,
                                                        int* __restrict__ rowptr,
                                                        int* __restrict__ col) {
    __shared__ int cnt[256];
    __shared__ int s[256];
    __shared__ int cur[256];
    int b = blockIdx.x, t = threadIdx.x;
    int e0 = base[b], e1 = e0 + total[b];
    cnt[t] = 0;
    __syncthreads();
    for (int e = e0 + t; e < e1; e += 256) atomicAdd(&cnt[ebuf[e] >> 24], 1);
    __syncthreads();
    int v = cnt[t];
    s[t] = v;
    __syncthreads();
    for (int off = 1; off < 256; off <<= 1) {
        int u = (t >= off) ? s[t - off] : 0;
        __syncthreads();
        s[t] += u;
        __syncthreads();
    }
    int start = e0 + s[t] - v;  // exclusive
    int node = (b << 8) + t;
    if (node < N) rowptr[node] = start;
    if (b == NB - 1 && t == 0) rowptr[N] = E;
    cur[t] = start;
    __syncthreads();
    for (int e = e0 + t; e < e1; e += 256) {
        uint ev = ebuf[e];
        int p = atomicAdd(&cur[ev >> 24], 1);
        col[p] = (int)(ev & 0xFFFFFFu);
    }
}

// ---------------- MFMA dual GEMM ----------------
// C cols of Y = bf16(X@Wa^T), C cols of Z = bias + X@Wb^T, stacked [Wa;Wb].
// Block: 256 thr = 4 waves (2x2), tile 128 rows x 128 stacked-cols.
// K=128 in two 64-wide LDS slabs. LDS row stride 72 bf16 (144 B: 16B-aligned,
// 36 words = 4 mod 32 -> uniform 8 words/bank for the b128 fragment reads).

#define LDK 72

template <int C, bool A_BF16>
__global__ __launch_bounds__(256, 2) void gemm_mfma(const void* __restrict__ Aptr,
                                                    const float* __restrict__ Wa,
                                                    const float* __restrict__ Wb,
                                                    const float* __restrict__ bias,
                                                    ushort* __restrict__ Y,
                                                    float* __restrict__ Z, int n_rows) {
    __shared__ ushort Xs[128 * LDK];
    __shared__ ushort Ws[128 * LDK];

    const int t = threadIdx.x;
    const int lane = t & 63;
    const int wave = t >> 6;
    const int wm = wave >> 1, wn = wave & 1;
    const int row0 = blockIdx.x * 128;
    const int tn = blockIdx.y;  // stacked-col tile (0: cols 0..127, 1: 128..255)
    const int fr = lane & 15;
    const int quad = lane >> 4;

    f32x4 acc[4][4];
#pragma unroll
    for (int i = 0; i < 4; i++)
#pragma unroll
        for (int j = 0; j < 4; j++) acc[i][j] = (f32x4){0.f, 0.f, 0.f, 0.f};

    for (int ko = 0; ko < 2; ++ko) {
        // ---- stage A slab: rows row0..+128, k = ko*64..+64 ----
        if (A_BF16) {
            const ushort* A = (const ushort*)Aptr;
#pragma unroll
            for (int j = 0; j < 4; ++j) {
                int f = j * 256 + t;         // 0..1023 uint4 chunks
                int r = f >> 3, c = f & 7;   // c: 8-bf16 chunk in 64-k slab
                int grow = row0 + r;
                uint4 v = make_uint4(0u, 0u, 0u, 0u);
                if (grow < n_rows)
                    v = *(const uint4*)(A + (size_t)grow * 128 + ko * 64 + c * 8);
                *(uint4*)(&Xs[r * LDK + c * 8]) = v;
            }
        } else {
            const float* A = (const float*)Aptr;
#pragma unroll
            for (int j = 0; j < 8; ++j) {
                int f = j * 256 + t;          // 0..2047 float4 chunks
                int r = f >> 4, c = f & 15;   // c: float4 in 64-k slab
                int grow = row0 + r;
                float4 v = make_float4(0.f, 0.f, 0.f, 0.f);
                if (grow < n_rows)
                    v = *(const float4*)(A + (size_t)grow * 128 + ko * 64 + c * 4);
                uint2 u;
                u.x = pack_bf16x2(v.x, v.y);
                u.y = pack_bf16x2(v.z, v.w);
                *(uint2*)(&Xs[r * LDK + c * 4]) = u;
            }
        }
        // ---- stage B slab: stacked rows tn*128..+128, k = ko*64..+64 ----
#pragma unroll
        for (int j = 0; j < 8; ++j) {
            int f = j * 256 + t;
            int r = f >> 4, c = f & 15;
            int grow = tn * 128 + r;
            const float* Wr = (grow < C) ? (Wa + (size_t)grow * 128)
                                         : (Wb + (size_t)(grow - C) * 128);
            float4 v = *(const float4*)(Wr + ko * 64 + c * 4);
            uint2 u;
            u.x = pack_bf16x2(v.x, v.y);
            u.y = pack_bf16x2(v.z, v.w);
            *(uint2*)(&Ws[r * LDK + c * 4]) = u;
        }
        __syncthreads();

        // ---- compute: 2 k-steps of 32 ----
#pragma unroll
        for (int ks = 0; ks < 2; ++ks) {
            bf16x8 a[4], b[4];
#pragma unroll
            for (int mt = 0; mt < 4; ++mt)
                a[mt] = *(const bf16x8*)(&Xs[(wm * 64 + mt * 16 + fr) * LDK +
                                             ks * 32 + quad * 8]);
#pragma unroll
            for (int nt = 0; nt < 4; ++nt)
                b[nt] = *(const bf16x8*)(&Ws[(wn * 64 + nt * 16 + fr) * LDK +
                                             ks * 32 + quad * 8]);
#pragma unroll
            for (int mt = 0; mt < 4; ++mt)
#pragma unroll
                for (int nt = 0; nt < 4; ++nt)
                    acc[mt][nt] = __builtin_amdgcn_mfma_f32_16x16x32_bf16(
                        a[mt], b[nt], acc[mt][nt], 0, 0, 0);
        }
        __syncthreads();
    }

    // ---- epilogue: C/D layout col=lane&15, row=quad*4+reg ----
#pragma unroll
    for (int nt = 0; nt < 4; ++nt) {
        int gcol = tn * 128 + wn * 64 + nt * 16 + fr;  // stacked col
        if (gcol < C) {
#pragma unroll
            for (int mt = 0; mt < 4; ++mt) {
#pragma unroll
                for (int r = 0; r < 4; ++r) {
                    int grow = row0 + wm * 64 + mt * 16 + quad * 4 + r;
                    if (grow < n_rows) {
                        __hip_bfloat16 hb = __float2bfloat16(acc[mt][nt][r]);
                        Y[(size_t)grow * C + gcol] = *(ushort*)&hb;
                    }
                }
            }
        } else {
            float bv = bias[gcol - C];
#pragma unroll
            for (int mt = 0; mt < 4; ++mt) {
#pragma unroll
                for (int r = 0; r < 4; ++r) {
                    int grow = row0 + wm * 64 + mt * 16 + quad * 4 + r;
                    if (grow < n_rows)
                        Z[(size_t)grow * C + (gcol - C)] = acc[mt][nt][r] + bv;
                }
            }
        }
    }
}

__device__ __forceinline__ float bflo(uint g) { return __uint_as_float(g << 16); }
__device__ __forceinline__ float bfhi(uint g) { return __uint_as_float(g & 0xffff0000u); }

// ---------------- aggregation ----------------
// layer 1: one wave per node, lane handles channels 2*lane, 2*lane+1.
// h written as bf16 (input to MFMA gemm2).

__global__ __launch_bounds__(256) void agg_relu_l1(const ushort* __restrict__ Y1,
                                                   const float* __restrict__ Z1,
                                                   const int* __restrict__ rowptr,
                                                   const int* __restrict__ col,
                                                   ushort* __restrict__ h, int n_nodes) {
    int node = (blockIdx.x * 256 + threadIdx.x) >> 6;
    if (node >= n_nodes) return;
    int lane = threadIdx.x & 63;
    const uint* Yv = (const uint*)Y1;  // row = 64 uints (128 bf16)
    int beg = rowptr[node], end = rowptr[node + 1];
    float ax = 0.f, ay = 0.f;
    int e = beg;
    for (; e + 4 <= end; e += 4) {
        int s0 = col[e], s1 = col[e + 1], s2 = col[e + 2], s3 = col[e + 3];
        uint ga = Yv[(long)s0 * 64 + lane];
        uint gb = Yv[(long)s1 * 64 + lane];
        uint gc = Yv[(long)s2 * 64 + lane];
        uint gd = Yv[(long)s3 * 64 + lane];
        ax += bflo(ga) + bflo(gb) + bflo(gc) + bflo(gd);
        ay += bfhi(ga) + bfhi(gb) + bfhi(gc) + bfhi(gd);
    }
    for (; e < end; ++e) {
        uint g = Yv[(long)col[e] * 64 + lane];
        ax += bflo(g);
        ay += bfhi(g);
    }
    float2 z = ((const float2*)Z1)[(long)node * 64 + lane];
    ax += z.x;
    ay += z.y;
    ax = ax > 0.f ? ax : 0.f;
    ay = ay > 0.f ? ay : 0.f;
    ((uint*)h)[(long)node * 64 + lane] = pack_bf16x2(ax, ay);
}

__global__ __launch_bounds__(256) void agg_l2(const ushort* __restrict__ Y2,
                                              const float* __restrict__ Z2,
                                              const int* __restrict__ rowptr,
                                              const int* __restrict__ col,
                                              float* __restrict__ out, int n_nodes) {
    int node = (blockIdx.x * 256 + threadIdx.x) >> 6;
    if (node >= n_nodes) return;
    int lane = threadIdx.x & 63;
    int beg = rowptr[node], end = rowptr[node + 1];
    float a = 0.f;
    int e = beg;
    for (; e + 4 <= end; e += 4) {
        int s0 = col[e], s1 = col[e + 1], s2 = col[e + 2], s3 = col[e + 3];
        float f0 = __uint_as_float((uint)Y2[(long)s0 * 64 + lane] << 16);
        float f1 = __uint_as_float((uint)Y2[(long)s1 * 64 + lane] << 16);
        float f2 = __uint_as_float((uint)Y2[(long)s2 * 64 + lane] << 16);
        float f3 = __uint_as_float((uint)Y2[(long)s3 * 64 + lane] << 16);
        a += f0 + f1 + f2 + f3;
    }
    for (; e < end; ++e)
        a += __uint_as_float((uint)Y2[(long)col[e] * 64 + lane] << 16);
    a += Z2[(long)node * 64 + lane];
    out[(long)node * 64 + lane] = a;
}

// ---------------- launch ----------------

extern "C" void kernel_launch(void* const* d_in, const int* in_sizes, int n_in,
                              void* d_out, int out_size, void* d_ws, size_t ws_size,
                              hipStream_t stream) {
    const float* x       = (const float*)d_in[0];
    const int*   ei      = (const int*)d_in[1];
    const float* W1_rel  = (const float*)d_in[2];
    const float* b1      = (const float*)d_in[3];
    const float* W1_root = (const float*)d_in[4];
    const float* W2_rel  = (const float*)d_in[5];
    const float* b2      = (const float*)d_in[6];
    const float* W2_root = (const float*)d_in[7];
    float* out = (float*)d_out;

    const int N = in_sizes[0] / 128;
    const int E = in_sizes[1] / 2;
    const int* srcA = ei;
    const int* dstA = ei + E;
    const int NB   = (N + 255) >> 8;
    const int NBLK = (E + EB - 1) / EB;

    char* ws = (char*)d_ws;
    size_t cur = 0;
    auto alloc = [&](size_t bytes) -> void* {
        size_t o = cur;
        cur = (cur + bytes + 511) & ~(size_t)511;
        return (void*)(ws + o);
    };
    ushort* Y1  = (ushort*)alloc((size_t)N * 128 * 2);
    float*  Z1  = (float*)alloc((size_t)N * 128 * 4);
    ushort* h   = (ushort*)alloc((size_t)N * 128 * 2);
    int* rowptr = (int*)alloc((size_t)(N + 1) * 4);
    int* colA   = (int*)alloc((size_t)E * 4);
    int* hist   = (int*)alloc((size_t)NBLK * NB * 4);
    int* btotal = (int*)alloc((size_t)NB_MAX * 4);
    int* bbase  = (int*)alloc((size_t)NB_MAX * 4);
    uint* ebuf  = (uint*)h;  // alias: ebuf dead before h is written
    ushort* Y2 = Y1;         // alias: Y1/Z1 dead after agg_relu_l1
    float*  Z2 = Z1;

    bucket_hist<<<NBLK, 256, 0, stream>>>(dstA, E, NB, hist);
    scan_blocks<<<NB, 256, 0, stream>>>(hist, NBLK, NB, btotal);
    scan_total<<<1, 512, 0, stream>>>(btotal, NB, bbase);
    bucket_scatter<<<NBLK, 256, 0, stream>>>(srcA, dstA, E, NB, hist, bbase, ebuf);
    build_csr_bucket<<<NB, 256, 0, stream>>>(ebuf, bbase, btotal, NB, N, E, rowptr, colA);

    const int gblk = (N + 127) / 128;
    gemm_mfma<128, false><<<dim3(gblk, 2), 256, 0, stream>>>(x, W1_rel, W1_root, b1,
                                                             Y1, Z1, N);
    agg_relu_l1<<<(N + 3) / 4, 256, 0, stream>>>(Y1, Z1, rowptr, colA, h, N);
    gemm_mfma<64, true><<<dim3(gblk, 1), 256, 0, stream>>>(h, W2_rel, W2_root, b2,
                                                           Y2, Z2, N);
    agg_l2<<<(N + 3) / 4, 256, 0, stream>>>(Y2, Z2, rowptr, colA, out, N);
}

// Round 5
// 486.691 us; speedup vs baseline: 1.9216x; 1.0761x over previous
//
#include <hip/hip_runtime.h>
#include <hip/hip_bf16.h>

// ---------------------------------------------------------------------------
// GraphConvEncoder: 2-layer GraphConv, transform-then-aggregate.
// GEMMs via bf16 MFMA (16x16x32), fp32 accumulate.
// y = x@W_rel^T stored bf16 (gathered E times); z = b + x@W_root^T fp32.
// h = relu(gather_sum(y1) + z1) stored bf16; out = gather_sum(y2) + z2 fp32.
// CSR via bucketed multisplit (no global atomics, no write-amp).
// Aggregation: unroll-8 gather (8 outstanding 256B loads/wave -> MLP-limited
// at unroll-4 per R4 Little's-law analysis: 585cyc avg latency, 42% peak).
// ---------------------------------------------------------------------------

#define EB 8192       // edges per block in bucket passes
#define NB_MAX 512    // max buckets (N <= 131072)

typedef __attribute__((ext_vector_type(8))) short bf16x8;
typedef __attribute__((ext_vector_type(4))) float f32x4;

__device__ __forceinline__ uint pack_bf16x2(float a, float b) {
    __hip_bfloat162 p = __float22bfloat162_rn(make_float2(a, b));
    return *(uint*)&p;  // low = a, high = b
}

// ---------------- CSR build: bucketed multisplit ----------------

__global__ __launch_bounds__(256) void bucket_hist(const int* __restrict__ dst, int E,
                                                   int NB, int* __restrict__ hist) {
    __shared__ int h[NB_MAX];
    int t = threadIdx.x;
    for (int i = t; i < NB; i += 256) h[i] = 0;
    __syncthreads();
    int e0 = blockIdx.x * EB, e1 = min(E, e0 + EB);
    for (int e = e0 + t; e < e1; e += 256) atomicAdd(&h[dst[e] >> 8], 1);
    __syncthreads();
    int* row = hist + (size_t)blockIdx.x * NB;
    for (int i = t; i < NB; i += 256) row[i] = h[i];
}

__global__ __launch_bounds__(256) void scan_blocks(int* __restrict__ hist, int NBLK,
                                                   int NB, int* __restrict__ total) {
    __shared__ int s[256];
    __shared__ int carry;
    int b = blockIdx.x, t = threadIdx.x;
    if (t == 0) carry = 0;
    __syncthreads();
    for (int start = 0; start < NBLK; start += 256) {
        int i = start + t;
        int v = (i < NBLK) ? hist[(size_t)i * NB + b] : 0;
        s[t] = v;
        __syncthreads();
        for (int off = 1; off < 256; off <<= 1) {
            int u = (t >= off) ? s[t - off] : 0;
            __syncthreads();
            s[t] += u;
            __syncthreads();
        }
        if (i < NBLK) hist[(size_t)i * NB + b] = carry + s[t] - v;
        __syncthreads();
        if (t == 255) carry += s[255];
        __syncthreads();
    }
    if (t == 0) total[b] = carry;
}

__global__ __launch_bounds__(512) void scan_total(const int* __restrict__ total, int NB,
                                                  int* __restrict__ base) {
    __shared__ int s[512];
    int t = threadIdx.x;
    int v = (t < NB) ? total[t] : 0;
    s[t] = v;
    __syncthreads();
    for (int off = 1; off < 512; off <<= 1) {
        int u = (t >= off) ? s[t - off] : 0;
        __syncthreads();
        s[t] += u;
        __syncthreads();
    }
    if (t < NB) base[t] = s[t] - v;
}

__global__ __launch_bounds__(256) void bucket_scatter(const int* __restrict__ src,
                                                      const int* __restrict__ dst, int E,
                                                      int NB, const int* __restrict__ hist,
                                                      const int* __restrict__ base,
                                                      uint* __restrict__ ebuf) {
    __shared__ int cur[NB_MAX];
    int t = threadIdx.x, blk = blockIdx.x;
    const int* row = hist + (size_t)blk * NB;
    for (int i = t; i < NB; i += 256) cur[i] = base[i] + row[i];
    __syncthreads();
    int e0 = blk * EB, e1 = min(E, e0 + EB);
    for (int e = e0 + t; e < e1; e += 256) {
        int d = dst[e];
        int p = atomicAdd(&cur[d >> 8], 1);
        ebuf[p] = ((uint)(d & 255) << 24) | (uint)src[e];
    }
}

__global__ __launch_bounds__(256) void build_csr_bucket(const uint* __restrict__ ebuf,
                                                        const int* __restrict__ base,
                                                        const int* __restrict__ total,
                                                        int NB, int N, int E,
                                                        int* __restrict__ rowptr,
                                                        int* __restrict__ col) {
    __shared__ int cnt[256];
    __shared__ int s[256];
    __shared__ int cur[256];
    int b = blockIdx.x, t = threadIdx.x;
    int e0 = base[b], e1 = e0 + total[b];
    cnt[t] = 0;
    __syncthreads();
    for (int e = e0 + t; e < e1; e += 256) atomicAdd(&cnt[ebuf[e] >> 24], 1);
    __syncthreads();
    int v = cnt[t];
    s[t] = v;
    __syncthreads();
    for (int off = 1; off < 256; off <<= 1) {
        int u = (t >= off) ? s[t - off] : 0;
        __syncthreads();
        s[t] += u;
        __syncthreads();
    }
    int start = e0 + s[t] - v;  // exclusive
    int node = (b << 8) + t;
    if (node < N) rowptr[node] = start;
    if (b == NB - 1 && t == 0) rowptr[N] = E;
    cur[t] = start;
    __syncthreads();
    for (int e = e0 + t; e < e1; e += 256) {
        uint ev = ebuf[e];
        int p = atomicAdd(&cur[ev >> 24], 1);
        col[p] = (int)(ev & 0xFFFFFFu);
    }
}

// ---------------- MFMA dual GEMM ----------------

#define LDK 72

template <int C, bool A_BF16>
__global__ __launch_bounds__(256, 2) void gemm_mfma(const void* __restrict__ Aptr,
                                                    const float* __restrict__ Wa,
                                                    const float* __restrict__ Wb,
                                                    const float* __restrict__ bias,
                                                    ushort* __restrict__ Y,
                                                    float* __restrict__ Z, int n_rows) {
    __shared__ ushort Xs[128 * LDK];
    __shared__ ushort Ws[128 * LDK];

    const int t = threadIdx.x;
    const int lane = t & 63;
    const int wave = t >> 6;
    const int wm = wave >> 1, wn = wave & 1;
    const int row0 = blockIdx.x * 128;
    const int tn = blockIdx.y;
    const int fr = lane & 15;
    const int quad = lane >> 4;

    f32x4 acc[4][4];
#pragma unroll
    for (int i = 0; i < 4; i++)
#pragma unroll
        for (int j = 0; j < 4; j++) acc[i][j] = (f32x4){0.f, 0.f, 0.f, 0.f};

    for (int ko = 0; ko < 2; ++ko) {
        if (A_BF16) {
            const ushort* A = (const ushort*)Aptr;
#pragma unroll
            for (int j = 0; j < 4; ++j) {
                int f = j * 256 + t;
                int r = f >> 3, c = f & 7;
                int grow = row0 + r;
                uint4 v = make_uint4(0u, 0u, 0u, 0u);
                if (grow < n_rows)
                    v = *(const uint4*)(A + (size_t)grow * 128 + ko * 64 + c * 8);
                *(uint4*)(&Xs[r * LDK + c * 8]) = v;
            }
        } else {
            const float* A = (const float*)Aptr;
#pragma unroll
            for (int j = 0; j < 8; ++j) {
                int f = j * 256 + t;
                int r = f >> 4, c = f & 15;
                int grow = row0 + r;
                float4 v = make_float4(0.f, 0.f, 0.f, 0.f);
                if (grow < n_rows)
                    v = *(const float4*)(A + (size_t)grow * 128 + ko * 64 + c * 4);
                uint2 u;
                u.x = pack_bf16x2(v.x, v.y);
                u.y = pack_bf16x2(v.z, v.w);
                *(uint2*)(&Xs[r * LDK + c * 4]) = u;
            }
        }
#pragma unroll
        for (int j = 0; j < 8; ++j) {
            int f = j * 256 + t;
            int r = f >> 4, c = f & 15;
            int grow = tn * 128 + r;
            const float* Wr = (grow < C) ? (Wa + (size_t)grow * 128)
                                         : (Wb + (size_t)(grow - C) * 128);
            float4 v = *(const float4*)(Wr + ko * 64 + c * 4);
            uint2 u;
            u.x = pack_bf16x2(v.x, v.y);
            u.y = pack_bf16x2(v.z, v.w);
            *(uint2*)(&Ws[r * LDK + c * 4]) = u;
        }
        __syncthreads();

#pragma unroll
        for (int ks = 0; ks < 2; ++ks) {
            bf16x8 a[4], b[4];
#pragma unroll
            for (int mt = 0; mt < 4; ++mt)
                a[mt] = *(const bf16x8*)(&Xs[(wm * 64 + mt * 16 + fr) * LDK +
                                             ks * 32 + quad * 8]);
#pragma unroll
            for (int nt = 0; nt < 4; ++nt)
                b[nt] = *(const bf16x8*)(&Ws[(wn * 64 + nt * 16 + fr) * LDK +
                                             ks * 32 + quad * 8]);
#pragma unroll
            for (int mt = 0; mt < 4; ++mt)
#pragma unroll
                for (int nt = 0; nt < 4; ++nt)
                    acc[mt][nt] = __builtin_amdgcn_mfma_f32_16x16x32_bf16(
                        a[mt], b[nt], acc[mt][nt], 0, 0, 0);
        }
        __syncthreads();
    }

#pragma unroll
    for (int nt = 0; nt < 4; ++nt) {
        int gcol = tn * 128 + wn * 64 + nt * 16 + fr;
        if (gcol < C) {
#pragma unroll
            for (int mt = 0; mt < 4; ++mt) {
#pragma unroll
                for (int r = 0; r < 4; ++r) {
                    int grow = row0 + wm * 64 + mt * 16 + quad * 4 + r;
                    if (grow < n_rows) {
                        __hip_bfloat16 hb = __float2bfloat16(acc[mt][nt][r]);
                        Y[(size_t)grow * C + gcol] = *(ushort*)&hb;
                    }
                }
            }
        } else {
            float bv = bias[gcol - C];
#pragma unroll
            for (int mt = 0; mt < 4; ++mt) {
#pragma unroll
                for (int r = 0; r < 4; ++r) {
                    int grow = row0 + wm * 64 + mt * 16 + quad * 4 + r;
                    if (grow < n_rows)
                        Z[(size_t)grow * C + (gcol - C)] = acc[mt][nt][r] + bv;
                }
            }
        }
    }
}

__device__ __forceinline__ float bflo(uint g) { return __uint_as_float(g << 16); }
__device__ __forceinline__ float bfhi(uint g) { return __uint_as_float(g & 0xffff0000u); }

// ---------------- aggregation ----------------
// layer 1: one wave per node, lane handles channels 2*lane, 2*lane+1.
// unroll-8: 8 independent row gathers in flight per wave (MLP).

__global__ __launch_bounds__(256) void agg_relu_l1(const ushort* __restrict__ Y1,
                                                   const float* __restrict__ Z1,
                                                   const int* __restrict__ rowptr,
                                                   const int* __restrict__ col,
                                                   ushort* __restrict__ h, int n_nodes) {
    int node = (blockIdx.x * 256 + threadIdx.x) >> 6;
    if (node >= n_nodes) return;
    int lane = threadIdx.x & 63;
    const uint* Yv = (const uint*)Y1;  // row = 64 uints (128 bf16)
    int beg = rowptr[node], end = rowptr[node + 1];
    float ax = 0.f, ay = 0.f, bx = 0.f, by = 0.f;
    int e = beg;
    for (; e + 8 <= end; e += 8) {
        int s0 = col[e], s1 = col[e + 1], s2 = col[e + 2], s3 = col[e + 3];
        int s4 = col[e + 4], s5 = col[e + 5], s6 = col[e + 6], s7 = col[e + 7];
        uint g0 = Yv[(long)s0 * 64 + lane];
        uint g1 = Yv[(long)s1 * 64 + lane];
        uint g2 = Yv[(long)s2 * 64 + lane];
        uint g3 = Yv[(long)s3 * 64 + lane];
        uint g4 = Yv[(long)s4 * 64 + lane];
        uint g5 = Yv[(long)s5 * 64 + lane];
        uint g6 = Yv[(long)s6 * 64 + lane];
        uint g7 = Yv[(long)s7 * 64 + lane];
        ax += bflo(g0) + bflo(g1) + bflo(g2) + bflo(g3);
        ay += bfhi(g0) + bfhi(g1) + bfhi(g2) + bfhi(g3);
        bx += bflo(g4) + bflo(g5) + bflo(g6) + bflo(g7);
        by += bfhi(g4) + bfhi(g5) + bfhi(g6) + bfhi(g7);
    }
    if (e + 4 <= end) {
        int s0 = col[e], s1 = col[e + 1], s2 = col[e + 2], s3 = col[e + 3];
        uint g0 = Yv[(long)s0 * 64 + lane];
        uint g1 = Yv[(long)s1 * 64 + lane];
        uint g2 = Yv[(long)s2 * 64 + lane];
        uint g3 = Yv[(long)s3 * 64 + lane];
        ax += bflo(g0) + bflo(g1) + bflo(g2) + bflo(g3);
        ay += bfhi(g0) + bfhi(g1) + bfhi(g2) + bfhi(g3);
        e += 4;
    }
    for (; e < end; ++e) {
        uint g = Yv[(long)col[e] * 64 + lane];
        ax += bflo(g);
        ay += bfhi(g);
    }
    ax += bx;
    ay += by;
    float2 z = ((const float2*)Z1)[(long)node * 64 + lane];
    ax += z.x;
    ay += z.y;
    ax = ax > 0.f ? ax : 0.f;
    ay = ay > 0.f ? ay : 0.f;
    ((uint*)h)[(long)node * 64 + lane] = pack_bf16x2(ax, ay);
}

// layer 2: one wave per node, lane handles channel `lane`, unroll-8.
__global__ __launch_bounds__(256) void agg_l2(const ushort* __restrict__ Y2,
                                              const float* __restrict__ Z2,
                                              const int* __restrict__ rowptr,
                                              const int* __restrict__ col,
                                              float* __restrict__ out, int n_nodes) {
    int node = (blockIdx.x * 256 + threadIdx.x) >> 6;
    if (node >= n_nodes) return;
    int lane = threadIdx.x & 63;
    int beg = rowptr[node], end = rowptr[node + 1];
    float a = 0.f, b = 0.f;
    int e = beg;
    for (; e + 8 <= end; e += 8) {
        int s0 = col[e], s1 = col[e + 1], s2 = col[e + 2], s3 = col[e + 3];
        int s4 = col[e + 4], s5 = col[e + 5], s6 = col[e + 6], s7 = col[e + 7];
        float f0 = __uint_as_float((uint)Y2[(long)s0 * 64 + lane] << 16);
        float f1 = __uint_as_float((uint)Y2[(long)s1 * 64 + lane] << 16);
        float f2 = __uint_as_float((uint)Y2[(long)s2 * 64 + lane] << 16);
        float f3 = __uint_as_float((uint)Y2[(long)s3 * 64 + lane] << 16);
        float f4 = __uint_as_float((uint)Y2[(long)s4 * 64 + lane] << 16);
        float f5 = __uint_as_float((uint)Y2[(long)s5 * 64 + lane] << 16);
        float f6 = __uint_as_float((uint)Y2[(long)s6 * 64 + lane] << 16);
        float f7 = __uint_as_float((uint)Y2[(long)s7 * 64 + lane] << 16);
        a += f0 + f1 + f2 + f3;
        b += f4 + f5 + f6 + f7;
    }
    if (e + 4 <= end) {
        int s0 = col[e], s1 = col[e + 1], s2 = col[e + 2], s3 = col[e + 3];
        float f0 = __uint_as_float((uint)Y2[(long)s0 * 64 + lane] << 16);
        float f1 = __uint_as_float((uint)Y2[(long)s1 * 64 + lane] << 16);
        float f2 = __uint_as_float((uint)Y2[(long)s2 * 64 + lane] << 16);
        float f3 = __uint_as_float((uint)Y2[(long)s3 * 64 + lane] << 16);
        a += f0 + f1 + f2 + f3;
        e += 4;
    }
    for (; e < end; ++e)
        a += __uint_as_float((uint)Y2[(long)col[e] * 64 + lane] << 16);
    a += b + Z2[(long)node * 64 + lane];
    out[(long)node * 64 + lane] = a;
}

// ---------------- launch ----------------

extern "C" void kernel_launch(void* const* d_in, const int* in_sizes, int n_in,
                              void* d_out, int out_size, void* d_ws, size_t ws_size,
                              hipStream_t stream) {
    const float* x       = (const float*)d_in[0];
    const int*   ei      = (const int*)d_in[1];
    const float* W1_rel  = (const float*)d_in[2];
    const float* b1      = (const float*)d_in[3];
    const float* W1_root = (const float*)d_in[4];
    const float* W2_rel  = (const float*)d_in[5];
    const float* b2      = (const float*)d_in[6];
    const float* W2_root = (const float*)d_in[7];
    float* out = (float*)d_out;

    const int N = in_sizes[0] / 128;
    const int E = in_sizes[1] / 2;
    const int* srcA = ei;
    const int* dstA = ei + E;
    const int NB   = (N + 255) >> 8;
    const int NBLK = (E + EB - 1) / EB;

    char* ws = (char*)d_ws;
    size_t cur = 0;
    auto alloc = [&](size_t bytes) -> void* {
        size_t o = cur;
        cur = (cur + bytes + 511) & ~(size_t)511;
        return (void*)(ws + o);
    };
    ushort* Y1  = (ushort*)alloc((size_t)N * 128 * 2);
    float*  Z1  = (float*)alloc((size_t)N * 128 * 4);
    ushort* h   = (ushort*)alloc((size_t)N * 128 * 2);
    int* rowptr = (int*)alloc((size_t)(N + 1) * 4);
    int* colA   = (int*)alloc((size_t)E * 4);
    int* hist   = (int*)alloc((size_t)NBLK * NB * 4);
    int* btotal = (int*)alloc((size_t)NB_MAX * 4);
    int* bbase  = (int*)alloc((size_t)NB_MAX * 4);
    uint* ebuf  = (uint*)h;  // alias: ebuf dead before h is written
    ushort* Y2 = Y1;         // alias: Y1/Z1 dead after agg_relu_l1
    float*  Z2 = Z1;

    bucket_hist<<<NBLK, 256, 0, stream>>>(dstA, E, NB, hist);
    scan_blocks<<<NB, 256, 0, stream>>>(hist, NBLK, NB, btotal);
    scan_total<<<1, 512, 0, stream>>>(btotal, NB, bbase);
    bucket_scatter<<<NBLK, 256, 0, stream>>>(srcA, dstA, E, NB, hist, bbase, ebuf);
    build_csr_bucket<<<NB, 256, 0, stream>>>(ebuf, bbase, btotal, NB, N, E, rowptr, colA);

    const int gblk = (N + 127) / 128;
    gemm_mfma<128, false><<<dim3(gblk, 2), 256, 0, stream>>>(x, W1_rel, W1_root, b1,
                                                             Y1, Z1, N);
    agg_relu_l1<<<(N + 3) / 4, 256, 0, stream>>>(Y1, Z1, rowptr, colA, h, N);
    gemm_mfma<64, true><<<dim3(gblk, 1), 256, 0, stream>>>(h, W2_rel, W2_root, b2,
                                                           Y2, Z2, N);
    agg_l2<<<(N + 3) / 4, 256, 0, stream>>>(Y2, Z2, rowptr, colA, out, N);
}

// Round 6
// 450.820 us; speedup vs baseline: 2.0745x; 1.0796x over previous
//
#include <hip/hip_runtime.h>
#include <hip/hip_bf16.h>

// ---------------------------------------------------------------------------
// GraphConvEncoder: 2-layer GraphConv, transform-then-aggregate.
// GEMMs via bf16 MFMA (16x16x32), fp32 accumulate.
// Gathered tables Y1/Y2 stored fp8 e4m3 (halves random-gather lines vs bf16;
// R5 showed the gather is service-rate-bound: unroll 4->8 gave only +10%).
// z = b + x@W_root^T fp32; h = relu(gather+z) bf16; out fp32.
// CSR via bucketed multisplit (no global atomics, no write-amp).
// ---------------------------------------------------------------------------

#define EB 8192       // edges per block in bucket passes
#define NB_MAX 512    // max buckets (N <= 131072)

typedef __attribute__((ext_vector_type(8))) short bf16x8;
typedef __attribute__((ext_vector_type(4))) float f32x4;
typedef __attribute__((ext_vector_type(2))) float f32x2;

__device__ __forceinline__ uint pack_bf16x2(float a, float b) {
    __hip_bfloat162 p = __float22bfloat162_rn(make_float2(a, b));
    return *(uint*)&p;  // low = a, high = b
}

__device__ __forceinline__ uchar pack_fp8(float v) {
    uint p = __builtin_amdgcn_cvt_pk_fp8_f32(v, v, 0, false);
    return (uchar)(p & 0xff);
}

// ---------------- CSR build: bucketed multisplit ----------------

__global__ __launch_bounds__(256) void bucket_hist(const int* __restrict__ dst, int E,
                                                   int NB, int* __restrict__ hist) {
    __shared__ int h[NB_MAX];
    int t = threadIdx.x;
    for (int i = t; i < NB; i += 256) h[i] = 0;
    __syncthreads();
    int e0 = blockIdx.x * EB, e1 = min(E, e0 + EB);
    for (int e = e0 + t; e < e1; e += 256) atomicAdd(&h[dst[e] >> 8], 1);
    __syncthreads();
    int* row = hist + (size_t)blockIdx.x * NB;
    for (int i = t; i < NB; i += 256) row[i] = h[i];
}

__global__ __launch_bounds__(256) void scan_blocks(int* __restrict__ hist, int NBLK,
                                                   int NB, int* __restrict__ total) {
    __shared__ int s[256];
    __shared__ int carry;
    int b = blockIdx.x, t = threadIdx.x;
    if (t == 0) carry = 0;
    __syncthreads();
    for (int start = 0; start < NBLK; start += 256) {
        int i = start + t;
        int v = (i < NBLK) ? hist[(size_t)i * NB + b] : 0;
        s[t] = v;
        __syncthreads();
        for (int off = 1; off < 256; off <<= 1) {
            int u = (t >= off) ? s[t - off] : 0;
            __syncthreads();
            s[t] += u;
            __syncthreads();
        }
        if (i < NBLK) hist[(size_t)i * NB + b] = carry + s[t] - v;
        __syncthreads();
        if (t == 255) carry += s[255];
        __syncthreads();
    }
    if (t == 0) total[b] = carry;
}

__global__ __launch_bounds__(512) void scan_total(const int* __restrict__ total, int NB,
                                                  int* __restrict__ base) {
    __shared__ int s[512];
    int t = threadIdx.x;
    int v = (t < NB) ? total[t] : 0;
    s[t] = v;
    __syncthreads();
    for (int off = 1; off < 512; off <<= 1) {
        int u = (t >= off) ? s[t - off] : 0;
        __syncthreads();
        s[t] += u;
        __syncthreads();
    }
    if (t < NB) base[t] = s[t] - v;
}

__global__ __launch_bounds__(256) void bucket_scatter(const int* __restrict__ src,
                                                      const int* __restrict__ dst, int E,
                                                      int NB, const int* __restrict__ hist,
                                                      const int* __restrict__ base,
                                                      uint* __restrict__ ebuf) {
    __shared__ int cur[NB_MAX];
    int t = threadIdx.x, blk = blockIdx.x;
    const int* row = hist + (size_t)blk * NB;
    for (int i = t; i < NB; i += 256) cur[i] = base[i] + row[i];
    __syncthreads();
    int e0 = blk * EB, e1 = min(E, e0 + EB);
    for (int e = e0 + t; e < e1; e += 256) {
        int d = dst[e];
        int p = atomicAdd(&cur[d >> 8], 1);
        ebuf[p] = ((uint)(d & 255) << 24) | (uint)src[e];
    }
}

__global__ __launch_bounds__(256) void build_csr_bucket(const uint* __restrict__ ebuf,
                                                        const int* __restrict__ base,
                                                        const int* __restrict__ total,
                                                        int NB, int N, int E,
                                                        int* __restrict__ rowptr,
                                                        int* __restrict__ col) {
    __shared__ int cnt[256];
    __shared__ int s[256];
    __shared__ int cur[256];
    int b = blockIdx.x, t = threadIdx.x;
    int e0 = base[b], e1 = e0 + total[b];
    cnt[t] = 0;
    __syncthreads();
    for (int e = e0 + t; e < e1; e += 256) atomicAdd(&cnt[ebuf[e] >> 24], 1);
    __syncthreads();
    int v = cnt[t];
    s[t] = v;
    __syncthreads();
    for (int off = 1; off < 256; off <<= 1) {
        int u = (t >= off) ? s[t - off] : 0;
        __syncthreads();
        s[t] += u;
        __syncthreads();
    }
    int start = e0 + s[t] - v;  // exclusive
    int node = (b << 8) + t;
    if (node < N) rowptr[node] = start;
    if (b == NB - 1 && t == 0) rowptr[N] = E;
    cur[t] = start;
    __syncthreads();
    for (int e = e0 + t; e < e1; e += 256) {
        uint ev = ebuf[e];
        int p = atomicAdd(&cur[ev >> 24], 1);
        col[p] = (int)(ev & 0xFFFFFFu);
    }
}

// ---------------- MFMA dual GEMM ----------------
// C cols of Y = fp8(X@Wa^T), C cols of Z = bias + X@Wb^T, stacked [Wa;Wb].

#define LDK 72

template <int C, bool A_BF16>
__global__ __launch_bounds__(256, 2) void gemm_mfma(const void* __restrict__ Aptr,
                                                    const float* __restrict__ Wa,
                                                    const float* __restrict__ Wb,
                                                    const float* __restrict__ bias,
                                                    uchar* __restrict__ Y,
                                                    float* __restrict__ Z, int n_rows) {
    __shared__ ushort Xs[128 * LDK];
    __shared__ ushort Ws[128 * LDK];

    const int t = threadIdx.x;
    const int lane = t & 63;
    const int wave = t >> 6;
    const int wm = wave >> 1, wn = wave & 1;
    const int row0 = blockIdx.x * 128;
    const int tn = blockIdx.y;
    const int fr = lane & 15;
    const int quad = lane >> 4;

    f32x4 acc[4][4];
#pragma unroll
    for (int i = 0; i < 4; i++)
#pragma unroll
        for (int j = 0; j < 4; j++) acc[i][j] = (f32x4){0.f, 0.f, 0.f, 0.f};

    for (int ko = 0; ko < 2; ++ko) {
        if (A_BF16) {
            const ushort* A = (const ushort*)Aptr;
#pragma unroll
            for (int j = 0; j < 4; ++j) {
                int f = j * 256 + t;
                int r = f >> 3, c = f & 7;
                int grow = row0 + r;
                uint4 v = make_uint4(0u, 0u, 0u, 0u);
                if (grow < n_rows)
                    v = *(const uint4*)(A + (size_t)grow * 128 + ko * 64 + c * 8);
                *(uint4*)(&Xs[r * LDK + c * 8]) = v;
            }
        } else {
            const float* A = (const float*)Aptr;
#pragma unroll
            for (int j = 0; j < 8; ++j) {
                int f = j * 256 + t;
                int r = f >> 4, c = f & 15;
                int grow = row0 + r;
                float4 v = make_float4(0.f, 0.f, 0.f, 0.f);
                if (grow < n_rows)
                    v = *(const float4*)(A + (size_t)grow * 128 + ko * 64 + c * 4);
                uint2 u;
                u.x = pack_bf16x2(v.x, v.y);
                u.y = pack_bf16x2(v.z, v.w);
                *(uint2*)(&Xs[r * LDK + c * 4]) = u;
            }
        }
#pragma unroll
        for (int j = 0; j < 8; ++j) {
            int f = j * 256 + t;
            int r = f >> 4, c = f & 15;
            int grow = tn * 128 + r;
            const float* Wr = (grow < C) ? (Wa + (size_t)grow * 128)
                                         : (Wb + (size_t)(grow - C) * 128);
            float4 v = *(const float4*)(Wr + ko * 64 + c * 4);
            uint2 u;
            u.x = pack_bf16x2(v.x, v.y);
            u.y = pack_bf16x2(v.z, v.w);
            *(uint2*)(&Ws[r * LDK + c * 4]) = u;
        }
        __syncthreads();

#pragma unroll
        for (int ks = 0; ks < 2; ++ks) {
            bf16x8 a[4], b[4];
#pragma unroll
            for (int mt = 0; mt < 4; ++mt)
                a[mt] = *(const bf16x8*)(&Xs[(wm * 64 + mt * 16 + fr) * LDK +
                                             ks * 32 + quad * 8]);
#pragma unroll
            for (int nt = 0; nt < 4; ++nt)
                b[nt] = *(const bf16x8*)(&Ws[(wn * 64 + nt * 16 + fr) * LDK +
                                             ks * 32 + quad * 8]);
#pragma unroll
            for (int mt = 0; mt < 4; ++mt)
#pragma unroll
                for (int nt = 0; nt < 4; ++nt)
                    acc[mt][nt] = __builtin_amdgcn_mfma_f32_16x16x32_bf16(
                        a[mt], b[nt], acc[mt][nt], 0, 0, 0);
        }
        __syncthreads();
    }

    // C/D layout: col = lane&15, row = quad*4 + reg
#pragma unroll
    for (int nt = 0; nt < 4; ++nt) {
        int gcol = tn * 128 + wn * 64 + nt * 16 + fr;
        if (gcol < C) {
#pragma unroll
            for (int mt = 0; mt < 4; ++mt) {
#pragma unroll
                for (int r = 0; r < 4; ++r) {
                    int grow = row0 + wm * 64 + mt * 16 + quad * 4 + r;
                    if (grow < n_rows)
                        Y[(size_t)grow * C + gcol] = pack_fp8(acc[mt][nt][r]);
                }
            }
        } else {
            float bv = bias[gcol - C];
#pragma unroll
            for (int mt = 0; mt < 4; ++mt) {
#pragma unroll
                for (int r = 0; r < 4; ++r) {
                    int grow = row0 + wm * 64 + mt * 16 + quad * 4 + r;
                    if (grow < n_rows)
                        Z[(size_t)grow * C + (gcol - C)] = acc[mt][nt][r] + bv;
                }
            }
        }
    }
}

// ---------------- aggregation ----------------
// layer 1: one wave per node, lane handles channels 2*lane, 2*lane+1.
// Y1 row = 128 fp8 bytes; lane loads ushort (2 fp8), HW cvt to 2 floats.

__global__ __launch_bounds__(256) void agg_relu_l1(const uchar* __restrict__ Y1,
                                                   const float* __restrict__ Z1,
                                                   const int* __restrict__ rowptr,
                                                   const int* __restrict__ col,
                                                   ushort* __restrict__ h, int n_nodes) {
    int node = (blockIdx.x * 256 + threadIdx.x) >> 6;
    if (node >= n_nodes) return;
    int lane = threadIdx.x & 63;
    const ushort* Yv = (const ushort*)Y1;  // row = 64 ushorts (128 fp8)
    int beg = rowptr[node], end = rowptr[node + 1];
    float ax = 0.f, ay = 0.f, bx = 0.f, by = 0.f;
    int e = beg;
    for (; e + 8 <= end; e += 8) {
        int s0 = col[e], s1 = col[e + 1], s2 = col[e + 2], s3 = col[e + 3];
        int s4 = col[e + 4], s5 = col[e + 5], s6 = col[e + 6], s7 = col[e + 7];
        int g0 = Yv[(long)s0 * 64 + lane];
        int g1 = Yv[(long)s1 * 64 + lane];
        int g2 = Yv[(long)s2 * 64 + lane];
        int g3 = Yv[(long)s3 * 64 + lane];
        int g4 = Yv[(long)s4 * 64 + lane];
        int g5 = Yv[(long)s5 * 64 + lane];
        int g6 = Yv[(long)s6 * 64 + lane];
        int g7 = Yv[(long)s7 * 64 + lane];
        f32x2 v0 = __builtin_amdgcn_cvt_pk_f32_fp8(g0, false);
        f32x2 v1 = __builtin_amdgcn_cvt_pk_f32_fp8(g1, false);
        f32x2 v2 = __builtin_amdgcn_cvt_pk_f32_fp8(g2, false);
        f32x2 v3 = __builtin_amdgcn_cvt_pk_f32_fp8(g3, false);
        f32x2 v4 = __builtin_amdgcn_cvt_pk_f32_fp8(g4, false);
        f32x2 v5 = __builtin_amdgcn_cvt_pk_f32_fp8(g5, false);
        f32x2 v6 = __builtin_amdgcn_cvt_pk_f32_fp8(g6, false);
        f32x2 v7 = __builtin_amdgcn_cvt_pk_f32_fp8(g7, false);
        ax += v0[0] + v1[0] + v2[0] + v3[0];
        ay += v0[1] + v1[1] + v2[1] + v3[1];
        bx += v4[0] + v5[0] + v6[0] + v7[0];
        by += v4[1] + v5[1] + v6[1] + v7[1];
    }
    if (e + 4 <= end) {
        int s0 = col[e], s1 = col[e + 1], s2 = col[e + 2], s3 = col[e + 3];
        int g0 = Yv[(long)s0 * 64 + lane];
        int g1 = Yv[(long)s1 * 64 + lane];
        int g2 = Yv[(long)s2 * 64 + lane];
        int g3 = Yv[(long)s3 * 64 + lane];
        f32x2 v0 = __builtin_amdgcn_cvt_pk_f32_fp8(g0, false);
        f32x2 v1 = __builtin_amdgcn_cvt_pk_f32_fp8(g1, false);
        f32x2 v2 = __builtin_amdgcn_cvt_pk_f32_fp8(g2, false);
        f32x2 v3 = __builtin_amdgcn_cvt_pk_f32_fp8(g3, false);
        ax += v0[0] + v1[0] + v2[0] + v3[0];
        ay += v0[1] + v1[1] + v2[1] + v3[1];
        e += 4;
    }
    for (; e < end; ++e) {
        int g = Yv[(long)col[e] * 64 + lane];
        f32x2 v = __builtin_amdgcn_cvt_pk_f32_fp8(g, false);
        ax += v[0];
        ay += v[1];
    }
    ax += bx;
    ay += by;
    float2 z = ((const float2*)Z1)[(long)node * 64 + lane];
    ax += z.x;
    ay += z.y;
    ax = ax > 0.f ? ax : 0.f;
    ay = ay > 0.f ? ay : 0.f;
    ((uint*)h)[(long)node * 64 + lane] = pack_bf16x2(ax, ay);
}

// layer 2: one wave per node, lane handles channel `lane` (1 fp8 byte; a
// whole row gather = one 64B line).
__global__ __launch_bounds__(256) void agg_l2(const uchar* __restrict__ Y2,
                                              const float* __restrict__ Z2,
                                              const int* __restrict__ rowptr,
                                              const int* __restrict__ col,
                                              float* __restrict__ out, int n_nodes) {
    int node = (blockIdx.x * 256 + threadIdx.x) >> 6;
    if (node >= n_nodes) return;
    int lane = threadIdx.x & 63;
    int beg = rowptr[node], end = rowptr[node + 1];
    float a = 0.f, b = 0.f;
    int e = beg;
    for (; e + 8 <= end; e += 8) {
        int s0 = col[e], s1 = col[e + 1], s2 = col[e + 2], s3 = col[e + 3];
        int s4 = col[e + 4], s5 = col[e + 5], s6 = col[e + 6], s7 = col[e + 7];
        int g0 = Y2[(long)s0 * 64 + lane];
        int g1 = Y2[(long)s1 * 64 + lane];
        int g2 = Y2[(long)s2 * 64 + lane];
        int g3 = Y2[(long)s3 * 64 + lane];
        int g4 = Y2[(long)s4 * 64 + lane];
        int g5 = Y2[(long)s5 * 64 + lane];
        int g6 = Y2[(long)s6 * 64 + lane];
        int g7 = Y2[(long)s7 * 64 + lane];
        a += __builtin_amdgcn_cvt_f32_fp8(g0, 0) + __builtin_amdgcn_cvt_f32_fp8(g1, 0) +
             __builtin_amdgcn_cvt_f32_fp8(g2, 0) + __builtin_amdgcn_cvt_f32_fp8(g3, 0);
        b += __builtin_amdgcn_cvt_f32_fp8(g4, 0) + __builtin_amdgcn_cvt_f32_fp8(g5, 0) +
             __builtin_amdgcn_cvt_f32_fp8(g6, 0) + __builtin_amdgcn_cvt_f32_fp8(g7, 0);
    }
    if (e + 4 <= end) {
        int s0 = col[e], s1 = col[e + 1], s2 = col[e + 2], s3 = col[e + 3];
        int g0 = Y2[(long)s0 * 64 + lane];
        int g1 = Y2[(long)s1 * 64 + lane];
        int g2 = Y2[(long)s2 * 64 + lane];
        int g3 = Y2[(long)s3 * 64 + lane];
        a += __builtin_amdgcn_cvt_f32_fp8(g0, 0) + __builtin_amdgcn_cvt_f32_fp8(g1, 0) +
             __builtin_amdgcn_cvt_f32_fp8(g2, 0) + __builtin_amdgcn_cvt_f32_fp8(g3, 0);
        e += 4;
    }
    for (; e < end; ++e)
        a += __builtin_amdgcn_cvt_f32_fp8((int)Y2[(long)col[e] * 64 + lane], 0);
    a += b + Z2[(long)node * 64 + lane];
    out[(long)node * 64 + lane] = a;
}

// ---------------- launch ----------------

extern "C" void kernel_launch(void* const* d_in, const int* in_sizes, int n_in,
                              void* d_out, int out_size, void* d_ws, size_t ws_size,
                              hipStream_t stream) {
    const float* x       = (const float*)d_in[0];
    const int*   ei      = (const int*)d_in[1];
    const float* W1_rel  = (const float*)d_in[2];
    const float* b1      = (const float*)d_in[3];
    const float* W1_root = (const float*)d_in[4];
    const float* W2_rel  = (const float*)d_in[5];
    const float* b2      = (const float*)d_in[6];
    const float* W2_root = (const float*)d_in[7];
    float* out = (float*)d_out;

    const int N = in_sizes[0] / 128;
    const int E = in_sizes[1] / 2;
    const int* srcA = ei;
    const int* dstA = ei + E;
    const int NB   = (N + 255) >> 8;
    const int NBLK = (E + EB - 1) / EB;

    char* ws = (char*)d_ws;
    size_t cur = 0;
    auto alloc = [&](size_t bytes) -> void* {
        size_t o = cur;
        cur = (cur + bytes + 511) & ~(size_t)511;
        return (void*)(ws + o);
    };
    uchar*  Y1  = (uchar*)alloc((size_t)N * 128);
    float*  Z1  = (float*)alloc((size_t)N * 128 * 4);
    ushort* h   = (ushort*)alloc((size_t)N * 128 * 2);
    int* rowptr = (int*)alloc((size_t)(N + 1) * 4);
    int* colA   = (int*)alloc((size_t)E * 4);
    int* hist   = (int*)alloc((size_t)NBLK * NB * 4);
    int* btotal = (int*)alloc((size_t)NB_MAX * 4);
    int* bbase  = (int*)alloc((size_t)NB_MAX * 4);
    uint* ebuf  = (uint*)h;  // alias: ebuf dead before h is written
    uchar* Y2 = Y1;          // alias: Y1/Z1 dead after agg_relu_l1
    float* Z2 = Z1;

    bucket_hist<<<NBLK, 256, 0, stream>>>(dstA, E, NB, hist);
    scan_blocks<<<NB, 256, 0, stream>>>(hist, NBLK, NB, btotal);
    scan_total<<<1, 512, 0, stream>>>(btotal, NB, bbase);
    bucket_scatter<<<NBLK, 256, 0, stream>>>(srcA, dstA, E, NB, hist, bbase, ebuf);
    build_csr_bucket<<<NB, 256, 0, stream>>>(ebuf, bbase, btotal, NB, N, E, rowptr, colA);

    const int gblk = (N + 127) / 128;
    gemm_mfma<128, false><<<dim3(gblk, 2), 256, 0, stream>>>(x, W1_rel, W1_root, b1,
                                                             Y1, Z1, N);
    agg_relu_l1<<<(N + 3) / 4, 256, 0, stream>>>(Y1, Z1, rowptr, colA, h, N);
    gemm_mfma<64, true><<<dim3(gblk, 1), 256, 0, stream>>>(h, W2_rel, W2_root, b2,
                                                           Y2, Z2, N);
    agg_l2<<<(N + 3) / 4, 256, 0, stream>>>(Y2, Z2, rowptr, colA, out, N);
}

// Round 7
// 425.160 us; speedup vs baseline: 2.1997x; 1.0604x over previous
//
#include <hip/hip_runtime.h>
#include <hip/hip_bf16.h>

// ---------------------------------------------------------------------------
// GraphConvEncoder: 2-layer GraphConv, transform-then-aggregate.
// GEMMs via bf16 MFMA (16x16x32), fp32 accumulate.
// Y1 = fp8(x@W1_rel^T) (gathered E times, 128B/row = 1 line);
// Y2 = bf16(h@W2_rel^T) (128B/row = 1 line; bf16 to keep absmax ~1.4 < 2.0).
// Gathers are VECTORIZED: lane loads uint4, 8 lanes/row -> 8 edges/instr
// (R6 decomposition: 54us instr/addr component + 29us line component;
//  8x fewer vmem instrs attacks the dominant term).
// CSR via bucketed multisplit (no global atomics, no write-amp).
// ---------------------------------------------------------------------------

#define EB 8192       // edges per block in bucket passes
#define NB_MAX 512    // max buckets (N <= 131072)

typedef __attribute__((ext_vector_type(8))) short bf16x8;
typedef __attribute__((ext_vector_type(4))) float f32x4;
typedef __attribute__((ext_vector_type(2))) float f32x2;

__device__ __forceinline__ uint pack_bf16x2(float a, float b) {
    __hip_bfloat162 p = __float22bfloat162_rn(make_float2(a, b));
    return *(uint*)&p;  // low = a, high = b
}

__device__ __forceinline__ uchar pack_fp8(float v) {
    uint p = __builtin_amdgcn_cvt_pk_fp8_f32(v, v, 0, false);
    return (uchar)(p & 0xff);
}

__device__ __forceinline__ float bflo(uint g) { return __uint_as_float(g << 16); }
__device__ __forceinline__ float bfhi(uint g) { return __uint_as_float(g & 0xffff0000u); }

// ---------------- CSR build: bucketed multisplit ----------------

__global__ __launch_bounds__(256) void bucket_hist(const int* __restrict__ dst, int E,
                                                   int NB, int* __restrict__ hist) {
    __shared__ int h[NB_MAX];
    int t = threadIdx.x;
    for (int i = t; i < NB; i += 256) h[i] = 0;
    __syncthreads();
    int e0 = blockIdx.x * EB, e1 = min(E, e0 + EB);
    for (int e = e0 + t; e < e1; e += 256) atomicAdd(&h[dst[e] >> 8], 1);
    __syncthreads();
    int* row = hist + (size_t)blockIdx.x * NB;
    for (int i = t; i < NB; i += 256) row[i] = h[i];
}

__global__ __launch_bounds__(256) void scan_blocks(int* __restrict__ hist, int NBLK,
                                                   int NB, int* __restrict__ total) {
    __shared__ int s[256];
    __shared__ int carry;
    int b = blockIdx.x, t = threadIdx.x;
    if (t == 0) carry = 0;
    __syncthreads();
    for (int start = 0; start < NBLK; start += 256) {
        int i = start + t;
        int v = (i < NBLK) ? hist[(size_t)i * NB + b] : 0;
        s[t] = v;
        __syncthreads();
        for (int off = 1; off < 256; off <<= 1) {
            int u = (t >= off) ? s[t - off] : 0;
            __syncthreads();
            s[t] += u;
            __syncthreads();
        }
        if (i < NBLK) hist[(size_t)i * NB + b] = carry + s[t] - v;
        __syncthreads();
        if (t == 255) carry += s[255];
        __syncthreads();
    }
    if (t == 0) total[b] = carry;
}

__global__ __launch_bounds__(512) void scan_total(const int* __restrict__ total, int NB,
                                                  int* __restrict__ base) {
    __shared__ int s[512];
    int t = threadIdx.x;
    int v = (t < NB) ? total[t] : 0;
    s[t] = v;
    __syncthreads();
    for (int off = 1; off < 512; off <<= 1) {
        int u = (t >= off) ? s[t - off] : 0;
        __syncthreads();
        s[t] += u;
        __syncthreads();
    }
    if (t < NB) base[t] = s[t] - v;
}

__global__ __launch_bounds__(256) void bucket_scatter(const int* __restrict__ src,
                                                      const int* __restrict__ dst, int E,
                                                      int NB, const int* __restrict__ hist,
                                                      const int* __restrict__ base,
                                                      uint* __restrict__ ebuf) {
    __shared__ int cur[NB_MAX];
    int t = threadIdx.x, blk = blockIdx.x;
    const int* row = hist + (size_t)blk * NB;
    for (int i = t; i < NB; i += 256) cur[i] = base[i] + row[i];
    __syncthreads();
    int e0 = blk * EB, e1 = min(E, e0 + EB);
    for (int e = e0 + t; e < e1; e += 256) {
        int d = dst[e];
        int p = atomicAdd(&cur[d >> 8], 1);
        ebuf[p] = ((uint)(d & 255) << 24) | (uint)src[e];
    }
}

__global__ __launch_bounds__(256) void build_csr_bucket(const uint* __restrict__ ebuf,
                                                        const int* __restrict__ base,
                                                        const int* __restrict__ total,
                                                        int NB, int N, int E,
                                                        int* __restrict__ rowptr,
                                                        int* __restrict__ col) {
    __shared__ int cnt[256];
    __shared__ int s[256];
    __shared__ int cur[256];
    int b = blockIdx.x, t = threadIdx.x;
    int e0 = base[b], e1 = e0 + total[b];
    cnt[t] = 0;
    __syncthreads();
    for (int e = e0 + t; e < e1; e += 256) atomicAdd(&cnt[ebuf[e] >> 24], 1);
    __syncthreads();
    int v = cnt[t];
    s[t] = v;
    __syncthreads();
    for (int off = 1; off < 256; off <<= 1) {
        int u = (t >= off) ? s[t - off] : 0;
        __syncthreads();
        s[t] += u;
        __syncthreads();
    }
    int start = e0 + s[t] - v;  // exclusive
    int node = (b << 8) + t;
    if (node < N) rowptr[node] = start;
    if (b == NB - 1 && t == 0) rowptr[N] = E;
    cur[t] = start;
    __syncthreads();
    for (int e = e0 + t; e < e1; e += 256) {
        uint ev = ebuf[e];
        int p = atomicAdd(&cur[ev >> 24], 1);
        col[p] = (int)(ev & 0xFFFFFFu);
    }
}

// ---------------- MFMA dual GEMM ----------------
// C cols of Y = fp8|bf16(X@Wa^T), C cols of Z = bias + X@Wb^T, stacked [Wa;Wb].

#define LDK 72

template <int C, bool A_BF16, bool Y_FP8>
__global__ __launch_bounds__(256, 2) void gemm_mfma(const void* __restrict__ Aptr,
                                                    const float* __restrict__ Wa,
                                                    const float* __restrict__ Wb,
                                                    const float* __restrict__ bias,
                                                    void* __restrict__ Yout,
                                                    float* __restrict__ Z, int n_rows) {
    __shared__ ushort Xs[128 * LDK];
    __shared__ ushort Ws[128 * LDK];

    const int t = threadIdx.x;
    const int lane = t & 63;
    const int wave = t >> 6;
    const int wm = wave >> 1, wn = wave & 1;
    const int row0 = blockIdx.x * 128;
    const int tn = blockIdx.y;
    const int fr = lane & 15;
    const int quad = lane >> 4;

    f32x4 acc[4][4];
#pragma unroll
    for (int i = 0; i < 4; i++)
#pragma unroll
        for (int j = 0; j < 4; j++) acc[i][j] = (f32x4){0.f, 0.f, 0.f, 0.f};

    for (int ko = 0; ko < 2; ++ko) {
        if (A_BF16) {
            const ushort* A = (const ushort*)Aptr;
#pragma unroll
            for (int j = 0; j < 4; ++j) {
                int f = j * 256 + t;
                int r = f >> 3, c = f & 7;
                int grow = row0 + r;
                uint4 v = make_uint4(0u, 0u, 0u, 0u);
                if (grow < n_rows)
                    v = *(const uint4*)(A + (size_t)grow * 128 + ko * 64 + c * 8);
                *(uint4*)(&Xs[r * LDK + c * 8]) = v;
            }
        } else {
            const float* A = (const float*)Aptr;
#pragma unroll
            for (int j = 0; j < 8; ++j) {
                int f = j * 256 + t;
                int r = f >> 4, c = f & 15;
                int grow = row0 + r;
                float4 v = make_float4(0.f, 0.f, 0.f, 0.f);
                if (grow < n_rows)
                    v = *(const float4*)(A + (size_t)grow * 128 + ko * 64 + c * 4);
                uint2 u;
                u.x = pack_bf16x2(v.x, v.y);
                u.y = pack_bf16x2(v.z, v.w);
                *(uint2*)(&Xs[r * LDK + c * 4]) = u;
            }
        }
#pragma unroll
        for (int j = 0; j < 8; ++j) {
            int f = j * 256 + t;
            int r = f >> 4, c = f & 15;
            int grow = tn * 128 + r;
            const float* Wr = (grow < C) ? (Wa + (size_t)grow * 128)
                                         : (Wb + (size_t)(grow - C) * 128);
            float4 v = *(const float4*)(Wr + ko * 64 + c * 4);
            uint2 u;
            u.x = pack_bf16x2(v.x, v.y);
            u.y = pack_bf16x2(v.z, v.w);
            *(uint2*)(&Ws[r * LDK + c * 4]) = u;
        }
        __syncthreads();

#pragma unroll
        for (int ks = 0; ks < 2; ++ks) {
            bf16x8 a[4], b[4];
#pragma unroll
            for (int mt = 0; mt < 4; ++mt)
                a[mt] = *(const bf16x8*)(&Xs[(wm * 64 + mt * 16 + fr) * LDK +
                                             ks * 32 + quad * 8]);
#pragma unroll
            for (int nt = 0; nt < 4; ++nt)
                b[nt] = *(const bf16x8*)(&Ws[(wn * 64 + nt * 16 + fr) * LDK +
                                             ks * 32 + quad * 8]);
#pragma unroll
            for (int mt = 0; mt < 4; ++mt)
#pragma unroll
                for (int nt = 0; nt < 4; ++nt)
                    acc[mt][nt] = __builtin_amdgcn_mfma_f32_16x16x32_bf16(
                        a[mt], b[nt], acc[mt][nt], 0, 0, 0);
        }
        __syncthreads();
    }

    // C/D layout: col = lane&15, row = quad*4 + reg
#pragma unroll
    for (int nt = 0; nt < 4; ++nt) {
        int gcol = tn * 128 + wn * 64 + nt * 16 + fr;
        if (gcol < C) {
#pragma unroll
            for (int mt = 0; mt < 4; ++mt) {
#pragma unroll
                for (int r = 0; r < 4; ++r) {
                    int grow = row0 + wm * 64 + mt * 16 + quad * 4 + r;
                    if (grow < n_rows) {
                        if (Y_FP8) {
                            ((uchar*)Yout)[(size_t)grow * C + gcol] =
                                pack_fp8(acc[mt][nt][r]);
                        } else {
                            __hip_bfloat16 hb = __float2bfloat16(acc[mt][nt][r]);
                            ((ushort*)Yout)[(size_t)grow * C + gcol] = *(ushort*)&hb;
                        }
                    }
                }
            }
        } else {
            float bv = bias[gcol - C];
#pragma unroll
            for (int mt = 0; mt < 4; ++mt) {
#pragma unroll
                for (int r = 0; r < 4; ++r) {
                    int grow = row0 + wm * 64 + mt * 16 + quad * 4 + r;
                    if (grow < n_rows)
                        Z[(size_t)grow * C + (gcol - C)] = acc[mt][nt][r] + bv;
                }
            }
        }
    }
}

// ---------------- aggregation (vectorized gather) ----------------
// layer 1: one wave per node. Y1 row = 128 fp8 B. Lane L: edge-slot L>>3,
// 16B chunk (L&7) -> one uint4 instr gathers 8 edges. Partial sums over 16
// channels/lane; shfl_xor(8,16,32) reduce; lanes 0..7 do z+relu epilogue.

__global__ __launch_bounds__(256) void agg_relu_l1(const uchar* __restrict__ Y1,
                                                   const float* __restrict__ Z1,
                                                   const int* __restrict__ rowptr,
                                                   const int* __restrict__ col,
                                                   ushort* __restrict__ h, int n_nodes) {
    int node = (blockIdx.x * 256 + threadIdx.x) >> 6;
    if (node >= n_nodes) return;
    int lane = threadIdx.x & 63;
    int sub = lane >> 3;   // edge slot within group of 8
    int cg  = lane & 7;    // channel group: channels cg*16 .. +15
    int beg = rowptr[node], end = rowptr[node + 1];
    float acc[16];
#pragma unroll
    for (int i = 0; i < 16; i++) acc[i] = 0.f;

    int e = beg;
    for (; e + 16 <= end; e += 16) {  // 2 groups in flight
        int s0 = col[e + sub];
        int s1 = col[e + 8 + sub];
        uint4 v0 = *(const uint4*)(Y1 + (size_t)s0 * 128 + cg * 16);
        uint4 v1 = *(const uint4*)(Y1 + (size_t)s1 * 128 + cg * 16);
        f32x2 p;
        p = __builtin_amdgcn_cvt_pk_f32_fp8(v0.x, false); acc[0] += p[0]; acc[1] += p[1];
        p = __builtin_amdgcn_cvt_pk_f32_fp8(v0.x, true);  acc[2] += p[0]; acc[3] += p[1];
        p = __builtin_amdgcn_cvt_pk_f32_fp8(v0.y, false); acc[4] += p[0]; acc[5] += p[1];
        p = __builtin_amdgcn_cvt_pk_f32_fp8(v0.y, true);  acc[6] += p[0]; acc[7] += p[1];
        p = __builtin_amdgcn_cvt_pk_f32_fp8(v0.z, false); acc[8] += p[0]; acc[9] += p[1];
        p = __builtin_amdgcn_cvt_pk_f32_fp8(v0.z, true);  acc[10] += p[0]; acc[11] += p[1];
        p = __builtin_amdgcn_cvt_pk_f32_fp8(v0.w, false); acc[12] += p[0]; acc[13] += p[1];
        p = __builtin_amdgcn_cvt_pk_f32_fp8(v0.w, true);  acc[14] += p[0]; acc[15] += p[1];
        p = __builtin_amdgcn_cvt_pk_f32_fp8(v1.x, false); acc[0] += p[0]; acc[1] += p[1];
        p = __builtin_amdgcn_cvt_pk_f32_fp8(v1.x, true);  acc[2] += p[0]; acc[3] += p[1];
        p = __builtin_amdgcn_cvt_pk_f32_fp8(v1.y, false); acc[4] += p[0]; acc[5] += p[1];
        p = __builtin_amdgcn_cvt_pk_f32_fp8(v1.y, true);  acc[6] += p[0]; acc[7] += p[1];
        p = __builtin_amdgcn_cvt_pk_f32_fp8(v1.z, false); acc[8] += p[0]; acc[9] += p[1];
        p = __builtin_amdgcn_cvt_pk_f32_fp8(v1.z, true);  acc[10] += p[0]; acc[11] += p[1];
        p = __builtin_amdgcn_cvt_pk_f32_fp8(v1.w, false); acc[12] += p[0]; acc[13] += p[1];
        p = __builtin_amdgcn_cvt_pk_f32_fp8(v1.w, true);  acc[14] += p[0]; acc[15] += p[1];
    }
    for (; e < end; e += 8) {  // masked tail groups
        int ee = e + sub;
        uint4 v = make_uint4(0u, 0u, 0u, 0u);
        if (ee < end)
            v = *(const uint4*)(Y1 + (size_t)col[ee] * 128 + cg * 16);
        f32x2 p;
        p = __builtin_amdgcn_cvt_pk_f32_fp8(v.x, false); acc[0] += p[0]; acc[1] += p[1];
        p = __builtin_amdgcn_cvt_pk_f32_fp8(v.x, true);  acc[2] += p[0]; acc[3] += p[1];
        p = __builtin_amdgcn_cvt_pk_f32_fp8(v.y, false); acc[4] += p[0]; acc[5] += p[1];
        p = __builtin_amdgcn_cvt_pk_f32_fp8(v.y, true);  acc[6] += p[0]; acc[7] += p[1];
        p = __builtin_amdgcn_cvt_pk_f32_fp8(v.z, false); acc[8] += p[0]; acc[9] += p[1];
        p = __builtin_amdgcn_cvt_pk_f32_fp8(v.z, true);  acc[10] += p[0]; acc[11] += p[1];
        p = __builtin_amdgcn_cvt_pk_f32_fp8(v.w, false); acc[12] += p[0]; acc[13] += p[1];
        p = __builtin_amdgcn_cvt_pk_f32_fp8(v.w, true);  acc[14] += p[0]; acc[15] += p[1];
    }

#pragma unroll
    for (int off = 8; off < 64; off <<= 1)
#pragma unroll
        for (int i = 0; i < 16; i++) acc[i] += __shfl_xor(acc[i], off, 64);

    if (sub == 0) {  // lanes 0..7: channels cg*16..+15
        const float4* zp = (const float4*)(Z1 + (size_t)node * 128 + cg * 16);
        uint o[8];
#pragma unroll
        for (int q = 0; q < 4; ++q) {
            float4 z = zp[q];
            float r0 = acc[q * 4 + 0] + z.x;
            float r1 = acc[q * 4 + 1] + z.y;
            float r2 = acc[q * 4 + 2] + z.z;
            float r3 = acc[q * 4 + 3] + z.w;
            r0 = r0 > 0.f ? r0 : 0.f;
            r1 = r1 > 0.f ? r1 : 0.f;
            r2 = r2 > 0.f ? r2 : 0.f;
            r3 = r3 > 0.f ? r3 : 0.f;
            o[q * 2 + 0] = pack_bf16x2(r0, r1);
            o[q * 2 + 1] = pack_bf16x2(r2, r3);
        }
        uint* hp = (uint*)(h + (size_t)node * 128) + cg * 8;
        *(uint4*)(hp + 0) = make_uint4(o[0], o[1], o[2], o[3]);
        *(uint4*)(hp + 4) = make_uint4(o[4], o[5], o[6], o[7]);
    }
}

// layer 2: one wave per node. Y2 row = 64 bf16 = 128 B. Lane L: edge slot
// L>>3, 16B chunk (L&7) = 8 channels. Same reduce/epilogue structure.

__global__ __launch_bounds__(256) void agg_l2(const ushort* __restrict__ Y2,
                                              const float* __restrict__ Z2,
                                              const int* __restrict__ rowptr,
                                              const int* __restrict__ col,
                                              float* __restrict__ out, int n_nodes) {
    int node = (blockIdx.x * 256 + threadIdx.x) >> 6;
    if (node >= n_nodes) return;
    int lane = threadIdx.x & 63;
    int sub = lane >> 3;
    int cg  = lane & 7;   // channels cg*8 .. +7
    int beg = rowptr[node], end = rowptr[node + 1];
    float acc[8];
#pragma unroll
    for (int i = 0; i < 8; i++) acc[i] = 0.f;

    int e = beg;
    for (; e + 16 <= end; e += 16) {
        int s0 = col[e + sub];
        int s1 = col[e + 8 + sub];
        uint4 v0 = *(const uint4*)(Y2 + (size_t)s0 * 64 + cg * 8);
        uint4 v1 = *(const uint4*)(Y2 + (size_t)s1 * 64 + cg * 8);
        acc[0] += bflo(v0.x) + bflo(v1.x);
        acc[1] += bfhi(v0.x) + bfhi(v1.x);
        acc[2] += bflo(v0.y) + bflo(v1.y);
        acc[3] += bfhi(v0.y) + bfhi(v1.y);
        acc[4] += bflo(v0.z) + bflo(v1.z);
        acc[5] += bfhi(v0.z) + bfhi(v1.z);
        acc[6] += bflo(v0.w) + bflo(v1.w);
        acc[7] += bfhi(v0.w) + bfhi(v1.w);
    }
    for (; e < end; e += 8) {
        int ee = e + sub;
        uint4 v = make_uint4(0u, 0u, 0u, 0u);
        if (ee < end)
            v = *(const uint4*)(Y2 + (size_t)col[ee] * 64 + cg * 8);
        acc[0] += bflo(v.x);
        acc[1] += bfhi(v.x);
        acc[2] += bflo(v.y);
        acc[3] += bfhi(v.y);
        acc[4] += bflo(v.z);
        acc[5] += bfhi(v.z);
        acc[6] += bflo(v.w);
        acc[7] += bfhi(v.w);
    }

#pragma unroll
    for (int off = 8; off < 64; off <<= 1)
#pragma unroll
        for (int i = 0; i < 8; i++) acc[i] += __shfl_xor(acc[i], off, 64);

    if (sub == 0) {  // lanes 0..7: channels cg*8..+7
        const float4* zp = (const float4*)(Z2 + (size_t)node * 64 + cg * 8);
        float4 z0 = zp[0], z1 = zp[1];
        float4 o0 = {acc[0] + z0.x, acc[1] + z0.y, acc[2] + z0.z, acc[3] + z0.w};
        float4 o1 = {acc[4] + z1.x, acc[5] + z1.y, acc[6] + z1.z, acc[7] + z1.w};
        float4* op = (float4*)(out + (size_t)node * 64 + cg * 8);
        op[0] = o0;
        op[1] = o1;
    }
}

// ---------------- launch ----------------

extern "C" void kernel_launch(void* const* d_in, const int* in_sizes, int n_in,
                              void* d_out, int out_size, void* d_ws, size_t ws_size,
                              hipStream_t stream) {
    const float* x       = (const float*)d_in[0];
    const int*   ei      = (const int*)d_in[1];
    const float* W1_rel  = (const float*)d_in[2];
    const float* b1      = (const float*)d_in[3];
    const float* W1_root = (const float*)d_in[4];
    const float* W2_rel  = (const float*)d_in[5];
    const float* b2      = (const float*)d_in[6];
    const float* W2_root = (const float*)d_in[7];
    float* out = (float*)d_out;

    const int N = in_sizes[0] / 128;
    const int E = in_sizes[1] / 2;
    const int* srcA = ei;
    const int* dstA = ei + E;
    const int NB   = (N + 255) >> 8;
    const int NBLK = (E + EB - 1) / EB;

    char* ws = (char*)d_ws;
    size_t cur = 0;
    auto alloc = [&](size_t bytes) -> void* {
        size_t o = cur;
        cur = (cur + bytes + 511) & ~(size_t)511;
        return (void*)(ws + o);
    };
    uchar*  Y1  = (uchar*)alloc((size_t)N * 128);        // fp8
    float*  Z1  = (float*)alloc((size_t)N * 128 * 4);
    ushort* h   = (ushort*)alloc((size_t)N * 128 * 2);   // bf16
    ushort* Y2  = (ushort*)alloc((size_t)N * 64 * 2);    // bf16
    float*  Z2  = (float*)alloc((size_t)N * 64 * 4);
    int* rowptr = (int*)alloc((size_t)(N + 1) * 4);
    int* colA   = (int*)alloc((size_t)E * 4);
    int* hist   = (int*)alloc((size_t)NBLK * NB * 4);
    int* btotal = (int*)alloc((size_t)NB_MAX * 4);
    int* bbase  = (int*)alloc((size_t)NB_MAX * 4);
    uint* ebuf  = (uint*)h;  // alias: ebuf dead before h is written

    bucket_hist<<<NBLK, 256, 0, stream>>>(dstA, E, NB, hist);
    scan_blocks<<<NB, 256, 0, stream>>>(hist, NBLK, NB, btotal);
    scan_total<<<1, 512, 0, stream>>>(btotal, NB, bbase);
    bucket_scatter<<<NBLK, 256, 0, stream>>>(srcA, dstA, E, NB, hist, bbase, ebuf);
    build_csr_bucket<<<NB, 256, 0, stream>>>(ebuf, bbase, btotal, NB, N, E, rowptr, colA);

    const int gblk = (N + 127) / 128;
    gemm_mfma<128, false, true><<<dim3(gblk, 2), 256, 0, stream>>>(
        x, W1_rel, W1_root, b1, Y1, Z1, N);
    agg_relu_l1<<<(N + 3) / 4, 256, 0, stream>>>(Y1, Z1, rowptr, colA, h, N);
    gemm_mfma<64, true, false><<<dim3(gblk, 1), 256, 0, stream>>>(
        h, W2_rel, W2_root, b2, Y2, Z2, N);
    agg_l2<<<(N + 3) / 4, 256, 0, stream>>>(Y2, Z2, rowptr, colA, out, N);
}